// Round 1
// baseline (200.761 us; speedup 1.0000x reference)
//
#include <hip/hip_runtime.h>
#include <hip/hip_bf16.h>

// GraphQNetwork: 2x GCNConv (9->32->64, relu) + global mean pool + station MLP.
// Round 14: edge partition rewritten as deterministic counting sort
// (hist -> per-graph scan -> scatter). Removes ALL global atomics: the old
// single-pass gsort spent ~100us with 256 blocks serializing 256 cross-XCD
// atomicAdds per cursor line. k_fused unchanged (r10 body, ~96us).

#define NNODES 262144
#define NPG 256
#define NGRAPHS 1024
#define NEDGES 2097152
#define NFEAT 9
#define ECAP2 2560
#define T_EDGES 8192
#define NTILES (NEDGES / T_EDGES)   // 256
#define TPB 512
#define NBLK 256

typedef __hip_bfloat16 bf16;
typedef short short8 __attribute__((ext_vector_type(8)));
typedef float f32x4 __attribute__((ext_vector_type(4)));

__device__ __forceinline__ float bfbits(unsigned short u) { return __uint_as_float(((unsigned)u) << 16); }
__device__ __forceinline__ unsigned short f2bbits(float v) { bf16 b = __float2bfloat16(v); return *(unsigned short*)&b; }

// ---- edge partition: deterministic counting sort, no global atomics --------

// A: per-tile per-graph histogram -> hist[tile][graph] (coalesced store)
__global__ void __launch_bounds__(1024) k_hist(const int* __restrict__ dst,
                                               int* __restrict__ hist) {
    __shared__ int cnt[NGRAPHS];
    int t = threadIdx.x;
    cnt[t] = 0;
    __syncthreads();
    const int4* d4 = (const int4*)(dst + blockIdx.x * T_EDGES);
#pragma unroll
    for (int k = 0; k < T_EDGES / 4096; ++k) {
        int4 dv = d4[k * 1024 + t];
        atomicAdd(&cnt[dv.x >> 8], 1);
        atomicAdd(&cnt[dv.y >> 8], 1);
        atomicAdd(&cnt[dv.z >> 8], 1);
        atomicAdd(&cnt[dv.w >> 8], 1);
    }
    __syncthreads();
    hist[blockIdx.x * NGRAPHS + t] = cnt[t];
}

// B: one block per graph: exclusive scan over its 256 tile counts (in-place),
// thread 255 writes the graph total to gcnt[g*16]. No memset needed.
__global__ void __launch_bounds__(256) k_scan(int* __restrict__ hist,
                                              int* __restrict__ gcnt) {
    __shared__ int wsum[4];
    int g = blockIdx.x;
    int t = threadIdx.x;            // tile index
    int lane = t & 63, wv = t >> 6;
    int v = hist[t * NGRAPHS + g];
    int inc = v;
    for (int off = 1; off < 64; off <<= 1) {
        int y = __shfl_up(inc, off);
        if (lane >= off) inc += y;
    }
    if (lane == 63) wsum[wv] = inc;
    __syncthreads();
    int wpre = 0;
#pragma unroll
    for (int w = 0; w < 3; ++w) if (w < wv) wpre += wsum[w];
    int exc = wpre + inc - v;
    hist[t * NGRAPHS + g] = exc;
    if (t == 255) gcnt[g * 16] = exc + v;
}

// C: scatter using precomputed per-(tile,graph) bases; LDS cursors only.
__global__ void __launch_bounds__(1024) k_scatter(const int* __restrict__ src,
                                                  const int* __restrict__ dst,
                                                  const int* __restrict__ hist,
                                                  unsigned short* __restrict__ gout) {
    __shared__ unsigned short edg[T_EDGES];
    __shared__ unsigned short pay[T_EDGES];
    __shared__ int cur[NGRAPHS];
    int t = threadIdx.x;
    int base = blockIdx.x * T_EDGES;
    cur[t] = hist[blockIdx.x * NGRAPHS + t];   // global exclusive base
    const int4* s4 = (const int4*)(src + base);
    const int4* d4 = (const int4*)(dst + base);
#pragma unroll
    for (int k = 0; k < T_EDGES / 4096; ++k) {
        int idx = k * 1024 + t;
        int4 dv = d4[idx];
        int4 sv = s4[idx];
        int i0 = idx * 4;
        edg[i0]     = (unsigned short)(dv.x >> 8);
        edg[i0 + 1] = (unsigned short)(dv.y >> 8);
        edg[i0 + 2] = (unsigned short)(dv.z >> 8);
        edg[i0 + 3] = (unsigned short)(dv.w >> 8);
        pay[i0]     = (unsigned short)(((dv.x & 255) << 8) | (sv.x & 255));
        pay[i0 + 1] = (unsigned short)(((dv.y & 255) << 8) | (sv.y & 255));
        pay[i0 + 2] = (unsigned short)(((dv.z & 255) << 8) | (sv.z & 255));
        pay[i0 + 3] = (unsigned short)(((dv.w & 255) << 8) | (sv.w & 255));
    }
    __syncthreads();
#pragma unroll
    for (int k = 0; k < T_EDGES / 1024; ++k) {
        int i = k * 1024 + t;
        int g = edg[i];
        int off = atomicAdd(&cur[g], 1);       // LDS cursor = global offset
        if (off < ECAP2) gout[(size_t)g * ECAP2 + off] = pay[i];
    }
}

// ---- persistent fused kernel: 256 blocks x 4 graphs (unchanged) ------------

__global__ void __launch_bounds__(TPB) k_fused(
    const float* __restrict__ x, const int* __restrict__ station_ids,
    const float* __restrict__ W1, const float* __restrict__ b1,
    const float* __restrict__ W2, const float* __restrict__ b2,
    const float* __restrict__ fc1W, const float* __restrict__ fc1b,
    const float* __restrict__ fc2W, const float* __restrict__ fc2b,
    const int* __restrict__ gcnt, const unsigned short* __restrict__ gedges,
    float* __restrict__ out) {

    __shared__ __align__(16) unsigned char Ms[65536];     // half-M: 128 x 512 B
    __shared__ __align__(16) unsigned char BufA[17024];   // G1T [32][266]
    __shared__ __align__(16) unsigned char BufB[17024];   // H1T [32][266]
    __shared__ __align__(16) unsigned char BufC[19456];   // xsf(9216)+EPa(5120) -> S2 [256][38]
    __shared__ __align__(16) unsigned short fc1s16[8192]; // bf16 [128][64] (persistent)
    __shared__ __align__(16) unsigned short W2Ts[64 * 40];
    __shared__ float W1s[288];
    __shared__ float dinvs[256];
    __shared__ unsigned short Rl[260];
    __shared__ unsigned char El[ECAP2];
    __shared__ unsigned int sru[512];
    __shared__ float sts[512];
    __shared__ float meanf[64];
    __shared__ float poolf[64];
    __shared__ unsigned char stmap[256];
    __shared__ float b1s[32], b2s[64], fc1bs[64], fc2ws[64];
    __shared__ int stids[8];
    __shared__ float fc2bv;

    int t = threadIdx.x;
    int lane = t & 63, wvid = t >> 6;                     // 8 waves
    int m = lane & 15, quad = lane >> 4;

    float* xsf = (float*)BufC;
    unsigned short* EPa = (unsigned short*)(BufC + 9216);
    unsigned short* G1T = (unsigned short*)BufA;
    unsigned short* H1T = (unsigned short*)BufB;
    unsigned short* S2 = (unsigned short*)BufC;

    // ---- persistent staging (once per block) ----
    for (int i = t; i < NFEAT * 32; i += TPB) W1s[i] = W1[i];
    for (int i = t; i < 2048; i += TPB)
        W2Ts[(i >> 5) * 40 + (i & 31)] = f2bbits(W2[(i & 31) * 64 + (i >> 5)]);
    for (int i = t; i < 8192; i += TPB) fc1s16[i] = f2bbits(fc1W[i]);
    if (t < 32) b1s[t] = b1[t];
    if (t < 64) { b2s[t] = b2[t]; fc1bs[t] = fc1b[t]; fc2ws[t] = fc2W[t]; }
    if (t < 8) stids[t] = station_ids[t];
    if (t == 0) fc2bv = fc2b[0];
    if (t < 256) stmap[t] = 255;
    __syncthreads();
    if (t < 8) stmap[stids[t] & 255] = (unsigned char)t;

    for (int g = blockIdx.x; g < NGRAPHS; g += NBLK) {
        int nbase = g * NPG;

        // ---- P0: per-graph staging + zero Ms
        int ecnt = min(gcnt[g * 16], ECAP2);
        {
            const uint4* gev = (const uint4*)(gedges + (size_t)g * ECAP2);
            uint4* epv = (uint4*)EPa;
            for (int i = t; i < ECAP2 / 8; i += TPB) epv[i] = gev[i];
        }
        const float* xg = x + (size_t)nbase * NFEAT;
        for (int i = t; i < NPG * NFEAT; i += TPB) xsf[i] = xg[i];
        if (t < 64) poolf[t] = 0.f;
        if (t < 256) sru[t] = 0u;
        {
            uint4* mz = (uint4*)Ms;
            uint4 z = {0u, 0u, 0u, 0u};
            for (int i = t; i < 4096; i += TPB) mz[i] = z;
        }
        __syncthreads();                                  // B1

        // ---- P0b: dst histogram
        for (int i = t; i < ecnt; i += TPB) atomicAdd(&sru[EPa[i] >> 8], 1u);
        __syncthreads();                                  // B2

        // ---- P0c: single-wave scan -> Rl, cursors, dinvs
        if (wvid == 0) {
            int b0 = sru[lane * 4], b1v = sru[lane * 4 + 1], b2v = sru[lane * 4 + 2], b3 = sru[lane * 4 + 3];
            int s = b0 + b1v + b2v + b3;
            int inc = s;
            for (int off = 1; off < 64; off <<= 1) {
                int y = __shfl_up(inc, off);
                if (lane >= off) inc += y;
            }
            int run = inc - s;
            Rl[lane * 4] = (unsigned short)run; sru[256 + lane * 4] = run;
            dinvs[lane * 4] = rsqrtf((float)(b0 + 1)); run += b0;
            Rl[lane * 4 + 1] = (unsigned short)run; sru[257 + lane * 4] = run;
            dinvs[lane * 4 + 1] = rsqrtf((float)(b1v + 1)); run += b1v;
            Rl[lane * 4 + 2] = (unsigned short)run; sru[258 + lane * 4] = run;
            dinvs[lane * 4 + 2] = rsqrtf((float)(b2v + 1)); run += b2v;
            Rl[lane * 4 + 3] = (unsigned short)run; sru[259 + lane * 4] = run;
            dinvs[lane * 4 + 3] = rsqrtf((float)(b3 + 1));
            if (lane == 63) Rl[256] = (unsigned short)inc;
        }
        __syncthreads();                                  // B3

        // ---- P0d: scatter -> El
        for (int i = t; i < ecnt; i += TPB) {
            unsigned short v = EPa[i];
            unsigned p = atomicAdd(&sru[256 + (v >> 8)], 1u);
            if (p < ECAP2) El[p] = (unsigned char)(v & 255);
        }
        __syncthreads();                                  // B4

        // ---- P1: t<256 builds M(h0) (2 thr/row); t>=256 lin1 -> G1T
        if (t < 256) {
            int dl = t >> 1, q = t & 1;
            int d = dl;
            float did = dinvs[d];
            if ((d >> 7) == q)
                *(unsigned short*)(Ms + dl * 512 + (((d >> 3) ^ (d & 15)) * 16) + (d & 7) * 2)
                    = f2bbits(did * did);
            int r0 = Rl[d], r1 = Rl[d + 1];
            for (int e = r0; e < r1; ++e) {
                int s = El[e];
                if ((s >> 7) == q) {
                    unsigned short* p =
                        (unsigned short*)(Ms + dl * 512 + (((s >> 3) ^ (d & 15)) * 16) + (s & 7) * 2);
                    *p = f2bbits(bfbits(*p) + did * dinvs[s]);
                }
            }
        } else {
            int n = t - 256;
            float xv[NFEAT];
#pragma unroll
            for (int k = 0; k < NFEAT; k++) xv[k] = xsf[n * NFEAT + k];
#pragma unroll 4
            for (int c = 0; c < 32; c++) {
                float acc = 0.f;
#pragma unroll
                for (int k = 0; k < NFEAT; k++) acc += xv[k] * W1s[k * 32 + c];
                G1T[c * 266 + n] = f2bbits(acc);
            }
        }
        __syncthreads();                                  // B5

        // ---- P2: agg1(h0) -> H1T nodes 0..127
        {
            f32x4 acc[2] = {};
            for (int kt = 0; kt < 8; ++kt) {
                short8 af = *(const short8*)(Ms + (wvid * 16 + m) * 512 + (((kt * 4 + quad) ^ m) * 16));
                short8 bf0 = *(const short8*)(BufA + (size_t)m * 532 + kt * 64 + quad * 16);
                short8 bf1 = *(const short8*)(BufA + (size_t)(16 + m) * 532 + kt * 64 + quad * 16);
                acc[0] = __builtin_amdgcn_mfma_f32_16x16x32_bf16(af, bf0, acc[0], 0, 0, 0);
                acc[1] = __builtin_amdgcn_mfma_f32_16x16x32_bf16(af, bf1, acc[1], 0, 0, 0);
            }
#pragma unroll
            for (int ni = 0; ni < 2; ++ni) {
                int ch = ni * 16 + m;
                float bb = b1s[ch];
#pragma unroll
                for (int r = 0; r < 4; ++r) {
                    int node = wvid * 16 + quad * 4 + r;
                    H1T[ch * 266 + node] = f2bbits(fmaxf(acc[ni][r] + bb, 0.f));
                }
            }
        }
        __syncthreads();                                  // B6

        // ---- P3: zero Ms; build M(h1) (4 thr/row)
        {
            uint4* mz = (uint4*)Ms;
            uint4 z = {0u, 0u, 0u, 0u};
            for (int i = t; i < 4096; i += TPB) mz[i] = z;
        }
        __syncthreads();                                  // B7
        {
            int dl = t >> 2, q = t & 3;
            int d = 128 + dl;
            float did = dinvs[d];
            if (((d & 255) >> 6) == q) {
                int sd = d & 255;
                *(unsigned short*)(Ms + dl * 512 + (((sd >> 3) ^ (d & 15)) * 16) + (sd & 7) * 2)
                    = f2bbits(did * did);
            }
            int r0 = Rl[d], r1 = Rl[d + 1];
            for (int e = r0; e < r1; ++e) {
                int s = El[e];
                if ((s >> 6) == q) {
                    unsigned short* p =
                        (unsigned short*)(Ms + dl * 512 + (((s >> 3) ^ (d & 15)) * 16) + (s & 7) * 2);
                    *p = f2bbits(bfbits(*p) + did * dinvs[s]);
                }
            }
        }
        __syncthreads();                                  // B8

        // ---- P4: agg1(h1) -> H1T nodes 128..255
        {
            f32x4 acc[2] = {};
            for (int kt = 0; kt < 8; ++kt) {
                short8 af = *(const short8*)(Ms + (wvid * 16 + m) * 512 + (((kt * 4 + quad) ^ m) * 16));
                short8 bf0 = *(const short8*)(BufA + (size_t)m * 532 + kt * 64 + quad * 16);
                short8 bf1 = *(const short8*)(BufA + (size_t)(16 + m) * 532 + kt * 64 + quad * 16);
                acc[0] = __builtin_amdgcn_mfma_f32_16x16x32_bf16(af, bf0, acc[0], 0, 0, 0);
                acc[1] = __builtin_amdgcn_mfma_f32_16x16x32_bf16(af, bf1, acc[1], 0, 0, 0);
            }
#pragma unroll
            for (int ni = 0; ni < 2; ++ni) {
                int ch = ni * 16 + m;
                float bb = b1s[ch];
#pragma unroll
                for (int r = 0; r < 4; ++r) {
                    int node = 128 + wvid * 16 + quad * 4 + r;
                    H1T[ch * 266 + node] = f2bbits(fmaxf(acc[ni][r] + bb, 0.f));
                }
            }
        }
        __syncthreads();                                  // B9

        // ---- P5: agg2'(h1) [M(h1) resident] -> S2 rows 128..255
        {
            f32x4 acc[2] = {};
            for (int kt = 0; kt < 8; ++kt) {
                short8 af = *(const short8*)(Ms + (wvid * 16 + m) * 512 + (((kt * 4 + quad) ^ m) * 16));
                short8 bf0 = *(const short8*)(BufB + (size_t)m * 532 + kt * 64 + quad * 16);
                short8 bf1 = *(const short8*)(BufB + (size_t)(16 + m) * 532 + kt * 64 + quad * 16);
                acc[0] = __builtin_amdgcn_mfma_f32_16x16x32_bf16(af, bf0, acc[0], 0, 0, 0);
                acc[1] = __builtin_amdgcn_mfma_f32_16x16x32_bf16(af, bf1, acc[1], 0, 0, 0);
            }
#pragma unroll
            for (int ni = 0; ni < 2; ++ni) {
                int ch = ni * 16 + m;
#pragma unroll
                for (int r = 0; r < 4; ++r) {
                    int node = 128 + wvid * 16 + quad * 4 + r;
                    S2[node * 38 + ch] = f2bbits(acc[ni][r]);
                }
            }
        }
        __syncthreads();                                  // B10

        // ---- P6: zero Ms; rebuild M(h0) (4 thr/row)
        {
            uint4* mz = (uint4*)Ms;
            uint4 z = {0u, 0u, 0u, 0u};
            for (int i = t; i < 4096; i += TPB) mz[i] = z;
        }
        __syncthreads();                                  // B11
        {
            int dl = t >> 2, q = t & 3;
            int d = dl;
            float did = dinvs[d];
            if ((d >> 6) == q)
                *(unsigned short*)(Ms + dl * 512 + (((d >> 3) ^ (d & 15)) * 16) + (d & 7) * 2)
                    = f2bbits(did * did);
            int r0 = Rl[d], r1 = Rl[d + 1];
            for (int e = r0; e < r1; ++e) {
                int s = El[e];
                if ((s >> 6) == q) {
                    unsigned short* p =
                        (unsigned short*)(Ms + dl * 512 + (((s >> 3) ^ (d & 15)) * 16) + (s & 7) * 2);
                    *p = f2bbits(bfbits(*p) + did * dinvs[s]);
                }
            }
        }
        __syncthreads();                                  // B12

        // ---- P7: agg2'(h0) -> S2 rows 0..127
        {
            f32x4 acc[2] = {};
            for (int kt = 0; kt < 8; ++kt) {
                short8 af = *(const short8*)(Ms + (wvid * 16 + m) * 512 + (((kt * 4 + quad) ^ m) * 16));
                short8 bf0 = *(const short8*)(BufB + (size_t)m * 532 + kt * 64 + quad * 16);
                short8 bf1 = *(const short8*)(BufB + (size_t)(16 + m) * 532 + kt * 64 + quad * 16);
                acc[0] = __builtin_amdgcn_mfma_f32_16x16x32_bf16(af, bf0, acc[0], 0, 0, 0);
                acc[1] = __builtin_amdgcn_mfma_f32_16x16x32_bf16(af, bf1, acc[1], 0, 0, 0);
            }
#pragma unroll
            for (int ni = 0; ni < 2; ++ni) {
                int ch = ni * 16 + m;
#pragma unroll
                for (int r = 0; r < 4; ++r) {
                    int node = wvid * 16 + quad * 4 + r;
                    S2[node * 38 + ch] = f2bbits(acc[ni][r]);
                }
            }
        }
        __syncthreads();                                  // B13

        // ---- P8: lin2 = relu(S2@W2+b2); pool + stations from accumulators
        {
#pragma unroll
            for (int mi = 0; mi < 2; ++mi) {
                int mt = wvid * 2 + mi;
                short8 af = *(const short8*)(BufC + (size_t)(mt * 16 + m) * 76 + quad * 16);
#pragma unroll
                for (int ni = 0; ni < 4; ++ni) {
                    short8 bf = *(const short8*)((const unsigned char*)W2Ts + (size_t)(ni * 16 + m) * 80 + quad * 16);
                    f32x4 c = {};
                    c = __builtin_amdgcn_mfma_f32_16x16x32_bf16(af, bf, c, 0, 0, 0);
                    int ch = ni * 16 + m;
                    float bb = b2s[ch];
                    float hv[4];
                    float p = 0.f;
#pragma unroll
                    for (int r = 0; r < 4; ++r) { hv[r] = fmaxf(c[r] + bb, 0.f); p += hv[r]; }
                    p += __shfl_down(p, 32);
                    p += __shfl_down(p, 16);
                    if (quad == 0) atomicAdd(&poolf[ch], p);
#pragma unroll
                    for (int r = 0; r < 4; ++r) {
                        int node = mt * 16 + quad * 4 + r;
                        int si = stmap[node];
                        if (si != 255) sts[si * 64 + ch] = hv[r];
                    }
                }
            }
        }
        __syncthreads();                                  // B14

        // ---- P9: mean
        if (t < 64) meanf[t] = poolf[t] * (1.0f / 256.0f);
        __syncthreads();                                  // B15

        // ---- P10: MLP, one wave per station
        {
            int l = lane;
            int si = wvid;
            const float* st = sts + si * 64;
            float acc = 0.f;
#pragma unroll 8
            for (int k = 0; k < 64; k++) acc += st[k] * bfbits(fc1s16[k * 64 + l]);
#pragma unroll 8
            for (int k = 0; k < 64; k++) acc += meanf[k] * bfbits(fc1s16[(64 + k) * 64 + l]);
            float a = fmaxf(acc + fc1bs[l], 0.f) * fc2ws[l];
            for (int off = 32; off > 0; off >>= 1) a += __shfl_down(a, off);
            if (l == 0) out[g * 8 + si] = a + fc2bv;
        }
        __syncthreads();                                  // B16 (loop hazard fence)
    }
}

// ---- launch -----------------------------------------------------------------

extern "C" void kernel_launch(void* const* d_in, const int* in_sizes, int n_in,
                              void* d_out, int out_size, void* d_ws, size_t ws_size,
                              hipStream_t stream) {
    const float* x = (const float*)d_in[0];
    const int* ei = (const int*)d_in[1];
    const int* station_ids = (const int*)d_in[2];
    const float* W1 = (const float*)d_in[3];
    const float* b1 = (const float*)d_in[4];
    const float* W2 = (const float*)d_in[5];
    const float* bias2 = (const float*)d_in[6];
    const float* fc1W = (const float*)d_in[7];
    const float* fc1b = (const float*)d_in[8];
    const float* fc2W = (const float*)d_in[9];
    const float* fc2b = (const float*)d_in[10];
    float* out = (float*)d_out;
    (void)in_sizes; (void)n_in; (void)out_size; (void)ws_size;

    char* ws = (char*)d_ws;
    int* gcnt = (int*)ws;                                     // 64 KiB, stride-16 totals
    unsigned short* gout = (unsigned short*)(ws + 0x10000);   // 5.24 MB
    int* hist = (int*)(ws + 0x510000);                        // 1 MB: [tile][graph]

    const int* esrc = ei;
    const int* edst = ei + NEDGES;

    k_hist<<<NTILES, 1024, 0, stream>>>(edst, hist);
    k_scan<<<NGRAPHS, 256, 0, stream>>>(hist, gcnt);
    k_scatter<<<NTILES, 1024, 0, stream>>>(esrc, edst, hist, gout);
    k_fused<<<NBLK, TPB, 0, stream>>>(x, station_ids, W1, b1, W2, bias2,
                                      fc1W, fc1b, fc2W, fc2b, gcnt, gout, out);
}

// Round 2
// 191.277 us; speedup vs baseline: 1.0496x; 1.0496x over previous
//
#include <hip/hip_runtime.h>
#include <hip/hip_bf16.h>

// GraphQNetwork: 2x GCNConv (9->32->64, relu) + global mean pool + station MLP.
// Round 15: k_scatter now counting-sorts the tile IN LDS first, then writes
// gout in sorted order so consecutive lanes hit consecutive addresses within
// each graph run (~5x fewer store transactions). r14's per-lane random 2B
// stores (64 lines per wave-store) are the suspected ~90us cost shared by
// r13/r14. k_hist/k_scan/k_fused unchanged.

#define NNODES 262144
#define NPG 256
#define NGRAPHS 1024
#define NEDGES 2097152
#define NFEAT 9
#define ECAP2 2560
#define T_EDGES 8192
#define NTILES (NEDGES / T_EDGES)   // 256
#define TPB 512
#define NBLK 256

typedef __hip_bfloat16 bf16;
typedef short short8 __attribute__((ext_vector_type(8)));
typedef float f32x4 __attribute__((ext_vector_type(4)));

__device__ __forceinline__ float bfbits(unsigned short u) { return __uint_as_float(((unsigned)u) << 16); }
__device__ __forceinline__ unsigned short f2bbits(float v) { bf16 b = __float2bfloat16(v); return *(unsigned short*)&b; }

// ---- edge partition: deterministic counting sort, no global atomics --------

// A: per-tile per-graph histogram -> hist[tile][graph] (coalesced store)
__global__ void __launch_bounds__(1024) k_hist(const int* __restrict__ dst,
                                               int* __restrict__ hist) {
    __shared__ int cnt[NGRAPHS];
    int t = threadIdx.x;
    cnt[t] = 0;
    __syncthreads();
    const int4* d4 = (const int4*)(dst + blockIdx.x * T_EDGES);
#pragma unroll
    for (int k = 0; k < T_EDGES / 4096; ++k) {
        int4 dv = d4[k * 1024 + t];
        atomicAdd(&cnt[dv.x >> 8], 1);
        atomicAdd(&cnt[dv.y >> 8], 1);
        atomicAdd(&cnt[dv.z >> 8], 1);
        atomicAdd(&cnt[dv.w >> 8], 1);
    }
    __syncthreads();
    hist[blockIdx.x * NGRAPHS + t] = cnt[t];
}

// B: one block per graph: exclusive scan over its 256 tile counts (in-place),
// thread 255 writes the graph total to gcnt[g*16]. No memset needed.
__global__ void __launch_bounds__(256) k_scan(int* __restrict__ hist,
                                              int* __restrict__ gcnt) {
    __shared__ int wsum[4];
    int g = blockIdx.x;
    int t = threadIdx.x;            // tile index
    int lane = t & 63, wv = t >> 6;
    int v = hist[t * NGRAPHS + g];
    int inc = v;
    for (int off = 1; off < 64; off <<= 1) {
        int y = __shfl_up(inc, off);
        if (lane >= off) inc += y;
    }
    if (lane == 63) wsum[wv] = inc;
    __syncthreads();
    int wpre = 0;
#pragma unroll
    for (int w = 0; w < 3; ++w) if (w < wv) wpre += wsum[w];
    int exc = wpre + inc - v;
    hist[t * NGRAPHS + g] = exc;
    if (t == 255) gcnt[g * 16] = exc + v;
}

// C: LDS counting sort of the tile, then sorted (coalescable) global stores.
__global__ void __launch_bounds__(1024) k_scatter(const int* __restrict__ src,
                                                  const int* __restrict__ dst,
                                                  const int* __restrict__ hist,
                                                  unsigned short* __restrict__ gout) {
    __shared__ unsigned short sg[T_EDGES];    // graph id per staged edge
    __shared__ unsigned short pay[T_EDGES];   // payload per staged edge
    __shared__ unsigned short spay[T_EDGES];  // graph-sorted payload
    __shared__ unsigned short ssg[T_EDGES];   // graph-sorted graph id
    __shared__ int cnt[NGRAPHS];              // histogram, then cursors
    __shared__ int lbase[NGRAPHS];            // local exclusive base in tile
    __shared__ int gb[NGRAPHS];               // global within-graph base (scan)
    __shared__ int wsum[16];
    int t = threadIdx.x;
    int lane = t & 63, wv = t >> 6;
    int base = blockIdx.x * T_EDGES;
    cnt[t] = 0;
    gb[t] = hist[blockIdx.x * NGRAPHS + t];
    __syncthreads();
    const int4* s4 = (const int4*)(src + base);
    const int4* d4 = (const int4*)(dst + base);
#pragma unroll
    for (int k = 0; k < T_EDGES / 4096; ++k) {
        int idx = k * 1024 + t;
        int4 dv = d4[idx];
        int4 sv = s4[idx];
        int i0 = idx * 4;
        sg[i0]     = (unsigned short)(dv.x >> 8);
        sg[i0 + 1] = (unsigned short)(dv.y >> 8);
        sg[i0 + 2] = (unsigned short)(dv.z >> 8);
        sg[i0 + 3] = (unsigned short)(dv.w >> 8);
        pay[i0]     = (unsigned short)(((dv.x & 255) << 8) | (sv.x & 255));
        pay[i0 + 1] = (unsigned short)(((dv.y & 255) << 8) | (sv.y & 255));
        pay[i0 + 2] = (unsigned short)(((dv.z & 255) << 8) | (sv.z & 255));
        pay[i0 + 3] = (unsigned short)(((dv.w & 255) << 8) | (sv.w & 255));
        atomicAdd(&cnt[dv.x >> 8], 1);
        atomicAdd(&cnt[dv.y >> 8], 1);
        atomicAdd(&cnt[dv.z >> 8], 1);
        atomicAdd(&cnt[dv.w >> 8], 1);
    }
    __syncthreads();
    // exclusive scan of cnt[1024] across 16 waves
    int c = cnt[t];
    int inc = c;
    for (int off = 1; off < 64; off <<= 1) {
        int y = __shfl_up(inc, off);
        if (lane >= off) inc += y;
    }
    if (lane == 63) wsum[wv] = inc;
    __syncthreads();
    int wpre = 0;
    for (int w = 0; w < wv; ++w) wpre += wsum[w];
    lbase[t] = wpre + inc - c;
    cnt[t] = 0;                               // reuse as scatter cursor
    __syncthreads();
    // LDS scatter into graph-sorted order
#pragma unroll
    for (int k = 0; k < T_EDGES / 1024; ++k) {
        int i = k * 1024 + t;
        int g = sg[i];
        int p = lbase[g] + atomicAdd(&cnt[g], 1);
        spay[p] = pay[i];
        ssg[p] = (unsigned short)g;
    }
    __syncthreads();
    // sorted store-out: consecutive lanes -> consecutive addresses per run
#pragma unroll
    for (int k = 0; k < T_EDGES / 1024; ++k) {
        int p = k * 1024 + t;
        int g = ssg[p];
        int off = gb[g] + (p - lbase[g]);
        if (off < ECAP2) gout[(size_t)g * ECAP2 + off] = spay[p];
    }
}

// ---- persistent fused kernel: 256 blocks x 4 graphs (unchanged) ------------

__global__ void __launch_bounds__(TPB) k_fused(
    const float* __restrict__ x, const int* __restrict__ station_ids,
    const float* __restrict__ W1, const float* __restrict__ b1,
    const float* __restrict__ W2, const float* __restrict__ b2,
    const float* __restrict__ fc1W, const float* __restrict__ fc1b,
    const float* __restrict__ fc2W, const float* __restrict__ fc2b,
    const int* __restrict__ gcnt, const unsigned short* __restrict__ gedges,
    float* __restrict__ out) {

    __shared__ __align__(16) unsigned char Ms[65536];     // half-M: 128 x 512 B
    __shared__ __align__(16) unsigned char BufA[17024];   // G1T [32][266]
    __shared__ __align__(16) unsigned char BufB[17024];   // H1T [32][266]
    __shared__ __align__(16) unsigned char BufC[19456];   // xsf(9216)+EPa(5120) -> S2 [256][38]
    __shared__ __align__(16) unsigned short fc1s16[8192]; // bf16 [128][64] (persistent)
    __shared__ __align__(16) unsigned short W2Ts[64 * 40];
    __shared__ float W1s[288];
    __shared__ float dinvs[256];
    __shared__ unsigned short Rl[260];
    __shared__ unsigned char El[ECAP2];
    __shared__ unsigned int sru[512];
    __shared__ float sts[512];
    __shared__ float meanf[64];
    __shared__ float poolf[64];
    __shared__ unsigned char stmap[256];
    __shared__ float b1s[32], b2s[64], fc1bs[64], fc2ws[64];
    __shared__ int stids[8];
    __shared__ float fc2bv;

    int t = threadIdx.x;
    int lane = t & 63, wvid = t >> 6;                     // 8 waves
    int m = lane & 15, quad = lane >> 4;

    float* xsf = (float*)BufC;
    unsigned short* EPa = (unsigned short*)(BufC + 9216);
    unsigned short* G1T = (unsigned short*)BufA;
    unsigned short* H1T = (unsigned short*)BufB;
    unsigned short* S2 = (unsigned short*)BufC;

    // ---- persistent staging (once per block) ----
    for (int i = t; i < NFEAT * 32; i += TPB) W1s[i] = W1[i];
    for (int i = t; i < 2048; i += TPB)
        W2Ts[(i >> 5) * 40 + (i & 31)] = f2bbits(W2[(i & 31) * 64 + (i >> 5)]);
    for (int i = t; i < 8192; i += TPB) fc1s16[i] = f2bbits(fc1W[i]);
    if (t < 32) b1s[t] = b1[t];
    if (t < 64) { b2s[t] = b2[t]; fc1bs[t] = fc1b[t]; fc2ws[t] = fc2W[t]; }
    if (t < 8) stids[t] = station_ids[t];
    if (t == 0) fc2bv = fc2b[0];
    if (t < 256) stmap[t] = 255;
    __syncthreads();
    if (t < 8) stmap[stids[t] & 255] = (unsigned char)t;

    for (int g = blockIdx.x; g < NGRAPHS; g += NBLK) {
        int nbase = g * NPG;

        // ---- P0: per-graph staging + zero Ms
        int ecnt = min(gcnt[g * 16], ECAP2);
        {
            const uint4* gev = (const uint4*)(gedges + (size_t)g * ECAP2);
            uint4* epv = (uint4*)EPa;
            for (int i = t; i < ECAP2 / 8; i += TPB) epv[i] = gev[i];
        }
        const float* xg = x + (size_t)nbase * NFEAT;
        for (int i = t; i < NPG * NFEAT; i += TPB) xsf[i] = xg[i];
        if (t < 64) poolf[t] = 0.f;
        if (t < 256) sru[t] = 0u;
        {
            uint4* mz = (uint4*)Ms;
            uint4 z = {0u, 0u, 0u, 0u};
            for (int i = t; i < 4096; i += TPB) mz[i] = z;
        }
        __syncthreads();                                  // B1

        // ---- P0b: dst histogram
        for (int i = t; i < ecnt; i += TPB) atomicAdd(&sru[EPa[i] >> 8], 1u);
        __syncthreads();                                  // B2

        // ---- P0c: single-wave scan -> Rl, cursors, dinvs
        if (wvid == 0) {
            int b0 = sru[lane * 4], b1v = sru[lane * 4 + 1], b2v = sru[lane * 4 + 2], b3 = sru[lane * 4 + 3];
            int s = b0 + b1v + b2v + b3;
            int inc = s;
            for (int off = 1; off < 64; off <<= 1) {
                int y = __shfl_up(inc, off);
                if (lane >= off) inc += y;
            }
            int run = inc - s;
            Rl[lane * 4] = (unsigned short)run; sru[256 + lane * 4] = run;
            dinvs[lane * 4] = rsqrtf((float)(b0 + 1)); run += b0;
            Rl[lane * 4 + 1] = (unsigned short)run; sru[257 + lane * 4] = run;
            dinvs[lane * 4 + 1] = rsqrtf((float)(b1v + 1)); run += b1v;
            Rl[lane * 4 + 2] = (unsigned short)run; sru[258 + lane * 4] = run;
            dinvs[lane * 4 + 2] = rsqrtf((float)(b2v + 1)); run += b2v;
            Rl[lane * 4 + 3] = (unsigned short)run; sru[259 + lane * 4] = run;
            dinvs[lane * 4 + 3] = rsqrtf((float)(b3 + 1));
            if (lane == 63) Rl[256] = (unsigned short)inc;
        }
        __syncthreads();                                  // B3

        // ---- P0d: scatter -> El
        for (int i = t; i < ecnt; i += TPB) {
            unsigned short v = EPa[i];
            unsigned p = atomicAdd(&sru[256 + (v >> 8)], 1u);
            if (p < ECAP2) El[p] = (unsigned char)(v & 255);
        }
        __syncthreads();                                  // B4

        // ---- P1: t<256 builds M(h0) (2 thr/row); t>=256 lin1 -> G1T
        if (t < 256) {
            int dl = t >> 1, q = t & 1;
            int d = dl;
            float did = dinvs[d];
            if ((d >> 7) == q)
                *(unsigned short*)(Ms + dl * 512 + (((d >> 3) ^ (d & 15)) * 16) + (d & 7) * 2)
                    = f2bbits(did * did);
            int r0 = Rl[d], r1 = Rl[d + 1];
            for (int e = r0; e < r1; ++e) {
                int s = El[e];
                if ((s >> 7) == q) {
                    unsigned short* p =
                        (unsigned short*)(Ms + dl * 512 + (((s >> 3) ^ (d & 15)) * 16) + (s & 7) * 2);
                    *p = f2bbits(bfbits(*p) + did * dinvs[s]);
                }
            }
        } else {
            int n = t - 256;
            float xv[NFEAT];
#pragma unroll
            for (int k = 0; k < NFEAT; k++) xv[k] = xsf[n * NFEAT + k];
#pragma unroll 4
            for (int c = 0; c < 32; c++) {
                float acc = 0.f;
#pragma unroll
                for (int k = 0; k < NFEAT; k++) acc += xv[k] * W1s[k * 32 + c];
                G1T[c * 266 + n] = f2bbits(acc);
            }
        }
        __syncthreads();                                  // B5

        // ---- P2: agg1(h0) -> H1T nodes 0..127
        {
            f32x4 acc[2] = {};
            for (int kt = 0; kt < 8; ++kt) {
                short8 af = *(const short8*)(Ms + (wvid * 16 + m) * 512 + (((kt * 4 + quad) ^ m) * 16));
                short8 bf0 = *(const short8*)(BufA + (size_t)m * 532 + kt * 64 + quad * 16);
                short8 bf1 = *(const short8*)(BufA + (size_t)(16 + m) * 532 + kt * 64 + quad * 16);
                acc[0] = __builtin_amdgcn_mfma_f32_16x16x32_bf16(af, bf0, acc[0], 0, 0, 0);
                acc[1] = __builtin_amdgcn_mfma_f32_16x16x32_bf16(af, bf1, acc[1], 0, 0, 0);
            }
#pragma unroll
            for (int ni = 0; ni < 2; ++ni) {
                int ch = ni * 16 + m;
                float bb = b1s[ch];
#pragma unroll
                for (int r = 0; r < 4; ++r) {
                    int node = wvid * 16 + quad * 4 + r;
                    H1T[ch * 266 + node] = f2bbits(fmaxf(acc[ni][r] + bb, 0.f));
                }
            }
        }
        __syncthreads();                                  // B6

        // ---- P3: zero Ms; build M(h1) (4 thr/row)
        {
            uint4* mz = (uint4*)Ms;
            uint4 z = {0u, 0u, 0u, 0u};
            for (int i = t; i < 4096; i += TPB) mz[i] = z;
        }
        __syncthreads();                                  // B7
        {
            int dl = t >> 2, q = t & 3;
            int d = 128 + dl;
            float did = dinvs[d];
            if (((d & 255) >> 6) == q) {
                int sd = d & 255;
                *(unsigned short*)(Ms + dl * 512 + (((sd >> 3) ^ (d & 15)) * 16) + (sd & 7) * 2)
                    = f2bbits(did * did);
            }
            int r0 = Rl[d], r1 = Rl[d + 1];
            for (int e = r0; e < r1; ++e) {
                int s = El[e];
                if ((s >> 6) == q) {
                    unsigned short* p =
                        (unsigned short*)(Ms + dl * 512 + (((s >> 3) ^ (d & 15)) * 16) + (s & 7) * 2);
                    *p = f2bbits(bfbits(*p) + did * dinvs[s]);
                }
            }
        }
        __syncthreads();                                  // B8

        // ---- P4: agg1(h1) -> H1T nodes 128..255
        {
            f32x4 acc[2] = {};
            for (int kt = 0; kt < 8; ++kt) {
                short8 af = *(const short8*)(Ms + (wvid * 16 + m) * 512 + (((kt * 4 + quad) ^ m) * 16));
                short8 bf0 = *(const short8*)(BufA + (size_t)m * 532 + kt * 64 + quad * 16);
                short8 bf1 = *(const short8*)(BufA + (size_t)(16 + m) * 532 + kt * 64 + quad * 16);
                acc[0] = __builtin_amdgcn_mfma_f32_16x16x32_bf16(af, bf0, acc[0], 0, 0, 0);
                acc[1] = __builtin_amdgcn_mfma_f32_16x16x32_bf16(af, bf1, acc[1], 0, 0, 0);
            }
#pragma unroll
            for (int ni = 0; ni < 2; ++ni) {
                int ch = ni * 16 + m;
                float bb = b1s[ch];
#pragma unroll
                for (int r = 0; r < 4; ++r) {
                    int node = 128 + wvid * 16 + quad * 4 + r;
                    H1T[ch * 266 + node] = f2bbits(fmaxf(acc[ni][r] + bb, 0.f));
                }
            }
        }
        __syncthreads();                                  // B9

        // ---- P5: agg2'(h1) [M(h1) resident] -> S2 rows 128..255
        {
            f32x4 acc[2] = {};
            for (int kt = 0; kt < 8; ++kt) {
                short8 af = *(const short8*)(Ms + (wvid * 16 + m) * 512 + (((kt * 4 + quad) ^ m) * 16));
                short8 bf0 = *(const short8*)(BufB + (size_t)m * 532 + kt * 64 + quad * 16);
                short8 bf1 = *(const short8*)(BufB + (size_t)(16 + m) * 532 + kt * 64 + quad * 16);
                acc[0] = __builtin_amdgcn_mfma_f32_16x16x32_bf16(af, bf0, acc[0], 0, 0, 0);
                acc[1] = __builtin_amdgcn_mfma_f32_16x16x32_bf16(af, bf1, acc[1], 0, 0, 0);
            }
#pragma unroll
            for (int ni = 0; ni < 2; ++ni) {
                int ch = ni * 16 + m;
#pragma unroll
                for (int r = 0; r < 4; ++r) {
                    int node = 128 + wvid * 16 + quad * 4 + r;
                    S2[node * 38 + ch] = f2bbits(acc[ni][r]);
                }
            }
        }
        __syncthreads();                                  // B10

        // ---- P6: zero Ms; rebuild M(h0) (4 thr/row)
        {
            uint4* mz = (uint4*)Ms;
            uint4 z = {0u, 0u, 0u, 0u};
            for (int i = t; i < 4096; i += TPB) mz[i] = z;
        }
        __syncthreads();                                  // B11
        {
            int dl = t >> 2, q = t & 3;
            int d = dl;
            float did = dinvs[d];
            if ((d >> 6) == q)
                *(unsigned short*)(Ms + dl * 512 + (((d >> 3) ^ (d & 15)) * 16) + (d & 7) * 2)
                    = f2bbits(did * did);
            int r0 = Rl[d], r1 = Rl[d + 1];
            for (int e = r0; e < r1; ++e) {
                int s = El[e];
                if ((s >> 6) == q) {
                    unsigned short* p =
                        (unsigned short*)(Ms + dl * 512 + (((s >> 3) ^ (d & 15)) * 16) + (s & 7) * 2);
                    *p = f2bbits(bfbits(*p) + did * dinvs[s]);
                }
            }
        }
        __syncthreads();                                  // B12

        // ---- P7: agg2'(h0) -> S2 rows 0..127
        {
            f32x4 acc[2] = {};
            for (int kt = 0; kt < 8; ++kt) {
                short8 af = *(const short8*)(Ms + (wvid * 16 + m) * 512 + (((kt * 4 + quad) ^ m) * 16));
                short8 bf0 = *(const short8*)(BufB + (size_t)m * 532 + kt * 64 + quad * 16);
                short8 bf1 = *(const short8*)(BufB + (size_t)(16 + m) * 532 + kt * 64 + quad * 16);
                acc[0] = __builtin_amdgcn_mfma_f32_16x16x32_bf16(af, bf0, acc[0], 0, 0, 0);
                acc[1] = __builtin_amdgcn_mfma_f32_16x16x32_bf16(af, bf1, acc[1], 0, 0, 0);
            }
#pragma unroll
            for (int ni = 0; ni < 2; ++ni) {
                int ch = ni * 16 + m;
#pragma unroll
                for (int r = 0; r < 4; ++r) {
                    int node = wvid * 16 + quad * 4 + r;
                    S2[node * 38 + ch] = f2bbits(acc[ni][r]);
                }
            }
        }
        __syncthreads();                                  // B13

        // ---- P8: lin2 = relu(S2@W2+b2); pool + stations from accumulators
        {
#pragma unroll
            for (int mi = 0; mi < 2; ++mi) {
                int mt = wvid * 2 + mi;
                short8 af = *(const short8*)(BufC + (size_t)(mt * 16 + m) * 76 + quad * 16);
#pragma unroll
                for (int ni = 0; ni < 4; ++ni) {
                    short8 bf = *(const short8*)((const unsigned char*)W2Ts + (size_t)(ni * 16 + m) * 80 + quad * 16);
                    f32x4 c = {};
                    c = __builtin_amdgcn_mfma_f32_16x16x32_bf16(af, bf, c, 0, 0, 0);
                    int ch = ni * 16 + m;
                    float bb = b2s[ch];
                    float hv[4];
                    float p = 0.f;
#pragma unroll
                    for (int r = 0; r < 4; ++r) { hv[r] = fmaxf(c[r] + bb, 0.f); p += hv[r]; }
                    p += __shfl_down(p, 32);
                    p += __shfl_down(p, 16);
                    if (quad == 0) atomicAdd(&poolf[ch], p);
#pragma unroll
                    for (int r = 0; r < 4; ++r) {
                        int node = mt * 16 + quad * 4 + r;
                        int si = stmap[node];
                        if (si != 255) sts[si * 64 + ch] = hv[r];
                    }
                }
            }
        }
        __syncthreads();                                  // B14

        // ---- P9: mean
        if (t < 64) meanf[t] = poolf[t] * (1.0f / 256.0f);
        __syncthreads();                                  // B15

        // ---- P10: MLP, one wave per station
        {
            int l = lane;
            int si = wvid;
            const float* st = sts + si * 64;
            float acc = 0.f;
#pragma unroll 8
            for (int k = 0; k < 64; k++) acc += st[k] * bfbits(fc1s16[k * 64 + l]);
#pragma unroll 8
            for (int k = 0; k < 64; k++) acc += meanf[k] * bfbits(fc1s16[(64 + k) * 64 + l]);
            float a = fmaxf(acc + fc1bs[l], 0.f) * fc2ws[l];
            for (int off = 32; off > 0; off >>= 1) a += __shfl_down(a, off);
            if (l == 0) out[g * 8 + si] = a + fc2bv;
        }
        __syncthreads();                                  // B16 (loop hazard fence)
    }
}

// ---- launch -----------------------------------------------------------------

extern "C" void kernel_launch(void* const* d_in, const int* in_sizes, int n_in,
                              void* d_out, int out_size, void* d_ws, size_t ws_size,
                              hipStream_t stream) {
    const float* x = (const float*)d_in[0];
    const int* ei = (const int*)d_in[1];
    const int* station_ids = (const int*)d_in[2];
    const float* W1 = (const float*)d_in[3];
    const float* b1 = (const float*)d_in[4];
    const float* W2 = (const float*)d_in[5];
    const float* bias2 = (const float*)d_in[6];
    const float* fc1W = (const float*)d_in[7];
    const float* fc1b = (const float*)d_in[8];
    const float* fc2W = (const float*)d_in[9];
    const float* fc2b = (const float*)d_in[10];
    float* out = (float*)d_out;
    (void)in_sizes; (void)n_in; (void)out_size; (void)ws_size;

    char* ws = (char*)d_ws;
    int* gcnt = (int*)ws;                                     // 64 KiB, stride-16 totals
    unsigned short* gout = (unsigned short*)(ws + 0x10000);   // 5.24 MB
    int* hist = (int*)(ws + 0x510000);                        // 1 MB: [tile][graph]

    const int* esrc = ei;
    const int* edst = ei + NEDGES;

    k_hist<<<NTILES, 1024, 0, stream>>>(edst, hist);
    k_scan<<<NGRAPHS, 256, 0, stream>>>(hist, gcnt);
    k_scatter<<<NTILES, 1024, 0, stream>>>(esrc, edst, hist, gout);
    k_fused<<<NBLK, TPB, 0, stream>>>(x, station_ids, W1, b1, W2, bias2,
                                      fc1W, fc1b, fc2W, fc2b, gcnt, gout, out);
}

// Round 3
// 188.038 us; speedup vs baseline: 1.0677x; 1.0172x over previous
//
#include <hip/hip_runtime.h>
#include <hip/hip_bf16.h>

// GraphQNetwork: 2x GCNConv (9->32->64, relu) + global mean pool + station MLP.
// Round 16: k_fused TPB 512 -> 1024 (16 waves, 4/SIMD instead of 2/SIMD).
// Same LDS (1 block/CU), same phase structure and swizzle formulas; every
// phase's work re-partitioned across 2x threads: M-build 8 thr/row (P3/P6),
// 4 thr/row (P1), lin1 2 thr/node, MFMA phases 1 N-tile/wave (was 2),
// P8 1 M-tile/wave (was 2). Goal: hide the LDS latency chains (75% idle,
// MfmaUtil 3.8%, VALUBusy 20%) with doubled TLP. Partition kernels unchanged.

#define NNODES 262144
#define NPG 256
#define NGRAPHS 1024
#define NEDGES 2097152
#define NFEAT 9
#define ECAP2 2560
#define T_EDGES 8192
#define NTILES (NEDGES / T_EDGES)   // 256
#define TPB 1024
#define NBLK 256

typedef __hip_bfloat16 bf16;
typedef short short8 __attribute__((ext_vector_type(8)));
typedef float f32x4 __attribute__((ext_vector_type(4)));

__device__ __forceinline__ float bfbits(unsigned short u) { return __uint_as_float(((unsigned)u) << 16); }
__device__ __forceinline__ unsigned short f2bbits(float v) { bf16 b = __float2bfloat16(v); return *(unsigned short*)&b; }

// ---- edge partition: deterministic counting sort, no global atomics --------

// A: per-tile per-graph histogram -> hist[tile][graph] (coalesced store)
__global__ void __launch_bounds__(1024) k_hist(const int* __restrict__ dst,
                                               int* __restrict__ hist) {
    __shared__ int cnt[NGRAPHS];
    int t = threadIdx.x;
    cnt[t] = 0;
    __syncthreads();
    const int4* d4 = (const int4*)(dst + blockIdx.x * T_EDGES);
#pragma unroll
    for (int k = 0; k < T_EDGES / 4096; ++k) {
        int4 dv = d4[k * 1024 + t];
        atomicAdd(&cnt[dv.x >> 8], 1);
        atomicAdd(&cnt[dv.y >> 8], 1);
        atomicAdd(&cnt[dv.z >> 8], 1);
        atomicAdd(&cnt[dv.w >> 8], 1);
    }
    __syncthreads();
    hist[blockIdx.x * NGRAPHS + t] = cnt[t];
}

// B: one block per graph: exclusive scan over its 256 tile counts (in-place),
// thread 255 writes the graph total to gcnt[g*16]. No memset needed.
__global__ void __launch_bounds__(256) k_scan(int* __restrict__ hist,
                                              int* __restrict__ gcnt) {
    __shared__ int wsum[4];
    int g = blockIdx.x;
    int t = threadIdx.x;            // tile index
    int lane = t & 63, wv = t >> 6;
    int v = hist[t * NGRAPHS + g];
    int inc = v;
    for (int off = 1; off < 64; off <<= 1) {
        int y = __shfl_up(inc, off);
        if (lane >= off) inc += y;
    }
    if (lane == 63) wsum[wv] = inc;
    __syncthreads();
    int wpre = 0;
#pragma unroll
    for (int w = 0; w < 3; ++w) if (w < wv) wpre += wsum[w];
    int exc = wpre + inc - v;
    hist[t * NGRAPHS + g] = exc;
    if (t == 255) gcnt[g * 16] = exc + v;
}

// C: LDS counting sort of the tile, then sorted (coalescable) global stores.
__global__ void __launch_bounds__(1024) k_scatter(const int* __restrict__ src,
                                                  const int* __restrict__ dst,
                                                  const int* __restrict__ hist,
                                                  unsigned short* __restrict__ gout) {
    __shared__ unsigned short sg[T_EDGES];    // graph id per staged edge
    __shared__ unsigned short pay[T_EDGES];   // payload per staged edge
    __shared__ unsigned short spay[T_EDGES];  // graph-sorted payload
    __shared__ unsigned short ssg[T_EDGES];   // graph-sorted graph id
    __shared__ int cnt[NGRAPHS];              // histogram, then cursors
    __shared__ int lbase[NGRAPHS];            // local exclusive base in tile
    __shared__ int gb[NGRAPHS];               // global within-graph base (scan)
    __shared__ int wsum[16];
    int t = threadIdx.x;
    int lane = t & 63, wv = t >> 6;
    int base = blockIdx.x * T_EDGES;
    cnt[t] = 0;
    gb[t] = hist[blockIdx.x * NGRAPHS + t];
    __syncthreads();
    const int4* s4 = (const int4*)(src + base);
    const int4* d4 = (const int4*)(dst + base);
#pragma unroll
    for (int k = 0; k < T_EDGES / 4096; ++k) {
        int idx = k * 1024 + t;
        int4 dv = d4[idx];
        int4 sv = s4[idx];
        int i0 = idx * 4;
        sg[i0]     = (unsigned short)(dv.x >> 8);
        sg[i0 + 1] = (unsigned short)(dv.y >> 8);
        sg[i0 + 2] = (unsigned short)(dv.z >> 8);
        sg[i0 + 3] = (unsigned short)(dv.w >> 8);
        pay[i0]     = (unsigned short)(((dv.x & 255) << 8) | (sv.x & 255));
        pay[i0 + 1] = (unsigned short)(((dv.y & 255) << 8) | (sv.y & 255));
        pay[i0 + 2] = (unsigned short)(((dv.z & 255) << 8) | (sv.z & 255));
        pay[i0 + 3] = (unsigned short)(((dv.w & 255) << 8) | (sv.w & 255));
        atomicAdd(&cnt[dv.x >> 8], 1);
        atomicAdd(&cnt[dv.y >> 8], 1);
        atomicAdd(&cnt[dv.z >> 8], 1);
        atomicAdd(&cnt[dv.w >> 8], 1);
    }
    __syncthreads();
    // exclusive scan of cnt[1024] across 16 waves
    int c = cnt[t];
    int inc = c;
    for (int off = 1; off < 64; off <<= 1) {
        int y = __shfl_up(inc, off);
        if (lane >= off) inc += y;
    }
    if (lane == 63) wsum[wv] = inc;
    __syncthreads();
    int wpre = 0;
    for (int w = 0; w < wv; ++w) wpre += wsum[w];
    lbase[t] = wpre + inc - c;
    cnt[t] = 0;                               // reuse as scatter cursor
    __syncthreads();
    // LDS scatter into graph-sorted order
#pragma unroll
    for (int k = 0; k < T_EDGES / 1024; ++k) {
        int i = k * 1024 + t;
        int g = sg[i];
        int p = lbase[g] + atomicAdd(&cnt[g], 1);
        spay[p] = pay[i];
        ssg[p] = (unsigned short)g;
    }
    __syncthreads();
    // sorted store-out: consecutive lanes -> consecutive addresses per run
#pragma unroll
    for (int k = 0; k < T_EDGES / 1024; ++k) {
        int p = k * 1024 + t;
        int g = ssg[p];
        int off = gb[g] + (p - lbase[g]);
        if (off < ECAP2) gout[(size_t)g * ECAP2 + off] = spay[p];
    }
}

// ---- persistent fused kernel: 256 blocks x 4 graphs, 16 waves --------------

__global__ void __launch_bounds__(TPB) k_fused(
    const float* __restrict__ x, const int* __restrict__ station_ids,
    const float* __restrict__ W1, const float* __restrict__ b1,
    const float* __restrict__ W2, const float* __restrict__ b2,
    const float* __restrict__ fc1W, const float* __restrict__ fc1b,
    const float* __restrict__ fc2W, const float* __restrict__ fc2b,
    const int* __restrict__ gcnt, const unsigned short* __restrict__ gedges,
    float* __restrict__ out) {

    __shared__ __align__(16) unsigned char Ms[65536];     // half-M: 128 x 512 B
    __shared__ __align__(16) unsigned char BufA[17024];   // G1T [32][266]
    __shared__ __align__(16) unsigned char BufB[17024];   // H1T [32][266]
    __shared__ __align__(16) unsigned char BufC[19456];   // xsf(9216)+EPa(5120) -> S2 [256][38]
    __shared__ __align__(16) unsigned short fc1s16[8192]; // bf16 [128][64] (persistent)
    __shared__ __align__(16) unsigned short W2Ts[64 * 40];
    __shared__ float W1s[288];
    __shared__ float dinvs[256];
    __shared__ unsigned short Rl[260];
    __shared__ unsigned char El[ECAP2];
    __shared__ unsigned int sru[512];
    __shared__ float sts[512];
    __shared__ float meanf[64];
    __shared__ float poolf[64];
    __shared__ unsigned char stmap[256];
    __shared__ float b1s[32], b2s[64], fc1bs[64], fc2ws[64];
    __shared__ int stids[8];
    __shared__ float fc2bv;

    int t = threadIdx.x;
    int lane = t & 63, wvid = t >> 6;                     // 16 waves
    int m = lane & 15, quad = lane >> 4;
    int wr = wvid >> 1, wn = wvid & 1;                    // row-tile / col-tile split

    float* xsf = (float*)BufC;
    unsigned short* EPa = (unsigned short*)(BufC + 9216);
    unsigned short* G1T = (unsigned short*)BufA;
    unsigned short* H1T = (unsigned short*)BufB;
    unsigned short* S2 = (unsigned short*)BufC;

    // ---- persistent staging (once per block) ----
    for (int i = t; i < NFEAT * 32; i += TPB) W1s[i] = W1[i];
    for (int i = t; i < 2048; i += TPB)
        W2Ts[(i >> 5) * 40 + (i & 31)] = f2bbits(W2[(i & 31) * 64 + (i >> 5)]);
    for (int i = t; i < 8192; i += TPB) fc1s16[i] = f2bbits(fc1W[i]);
    if (t < 32) b1s[t] = b1[t];
    if (t < 64) { b2s[t] = b2[t]; fc1bs[t] = fc1b[t]; fc2ws[t] = fc2W[t]; }
    if (t < 8) stids[t] = station_ids[t];
    if (t == 0) fc2bv = fc2b[0];
    if (t < 256) stmap[t] = 255;
    __syncthreads();
    if (t < 8) stmap[stids[t] & 255] = (unsigned char)t;

    for (int g = blockIdx.x; g < NGRAPHS; g += NBLK) {
        int nbase = g * NPG;

        // ---- P0: per-graph staging + zero Ms
        int ecnt = min(gcnt[g * 16], ECAP2);
        {
            const uint4* gev = (const uint4*)(gedges + (size_t)g * ECAP2);
            uint4* epv = (uint4*)EPa;
            for (int i = t; i < ECAP2 / 8; i += TPB) epv[i] = gev[i];
        }
        const float* xg = x + (size_t)nbase * NFEAT;
        for (int i = t; i < NPG * NFEAT; i += TPB) xsf[i] = xg[i];
        if (t < 64) poolf[t] = 0.f;
        if (t < 256) sru[t] = 0u;
        {
            uint4* mz = (uint4*)Ms;
            uint4 z = {0u, 0u, 0u, 0u};
            for (int i = t; i < 4096; i += TPB) mz[i] = z;
        }
        __syncthreads();                                  // B1

        // ---- P0b: dst histogram
        for (int i = t; i < ecnt; i += TPB) atomicAdd(&sru[EPa[i] >> 8], 1u);
        __syncthreads();                                  // B2

        // ---- P0c: single-wave scan -> Rl, cursors, dinvs
        if (wvid == 0) {
            int b0 = sru[lane * 4], b1v = sru[lane * 4 + 1], b2v = sru[lane * 4 + 2], b3 = sru[lane * 4 + 3];
            int s = b0 + b1v + b2v + b3;
            int inc = s;
            for (int off = 1; off < 64; off <<= 1) {
                int y = __shfl_up(inc, off);
                if (lane >= off) inc += y;
            }
            int run = inc - s;
            Rl[lane * 4] = (unsigned short)run; sru[256 + lane * 4] = run;
            dinvs[lane * 4] = rsqrtf((float)(b0 + 1)); run += b0;
            Rl[lane * 4 + 1] = (unsigned short)run; sru[257 + lane * 4] = run;
            dinvs[lane * 4 + 1] = rsqrtf((float)(b1v + 1)); run += b1v;
            Rl[lane * 4 + 2] = (unsigned short)run; sru[258 + lane * 4] = run;
            dinvs[lane * 4 + 2] = rsqrtf((float)(b2v + 1)); run += b2v;
            Rl[lane * 4 + 3] = (unsigned short)run; sru[259 + lane * 4] = run;
            dinvs[lane * 4 + 3] = rsqrtf((float)(b3 + 1));
            if (lane == 63) Rl[256] = (unsigned short)inc;
        }
        __syncthreads();                                  // B3

        // ---- P0d: scatter -> El
        for (int i = t; i < ecnt; i += TPB) {
            unsigned short v = EPa[i];
            unsigned p = atomicAdd(&sru[256 + (v >> 8)], 1u);
            if (p < ECAP2) El[p] = (unsigned char)(v & 255);
        }
        __syncthreads();                                  // B4

        // ---- P1: t<512 builds M(h0) rows 0..127 (4 thr/row); t>=512 lin1 -> G1T
        if (t < 512) {
            int dl = t >> 2, q = t & 3;
            int d = dl;
            float did = dinvs[d];
            if ((d >> 6) == q)
                *(unsigned short*)(Ms + dl * 512 + (((d >> 3) ^ (d & 15)) * 16) + (d & 7) * 2)
                    = f2bbits(did * did);
            int r0 = Rl[d], r1 = Rl[d + 1];
            for (int e = r0; e < r1; ++e) {
                int s = El[e];
                if ((s >> 6) == q) {
                    unsigned short* p =
                        (unsigned short*)(Ms + dl * 512 + (((s >> 3) ^ (d & 15)) * 16) + (s & 7) * 2);
                    *p = f2bbits(bfbits(*p) + did * dinvs[s]);
                }
            }
        } else {
            int tt = t - 512;
            int n = tt >> 1, half = tt & 1;
            float xv[NFEAT];
#pragma unroll
            for (int k = 0; k < NFEAT; k++) xv[k] = xsf[n * NFEAT + k];
            int c0 = half * 16;
#pragma unroll 4
            for (int ci = 0; ci < 16; ci++) {
                int c = c0 + ci;
                float acc = 0.f;
#pragma unroll
                for (int k = 0; k < NFEAT; k++) acc += xv[k] * W1s[k * 32 + c];
                G1T[c * 266 + n] = f2bbits(acc);
            }
        }
        __syncthreads();                                  // B5

        // ---- P2: agg1(h0) -> H1T nodes 0..127 (wave = (row-tile, col-tile))
        {
            f32x4 acc = {};
            for (int kt = 0; kt < 8; ++kt) {
                short8 af = *(const short8*)(Ms + (wr * 16 + m) * 512 + (((kt * 4 + quad) ^ m) * 16));
                short8 bf = *(const short8*)(BufA + (size_t)(wn * 16 + m) * 532 + kt * 64 + quad * 16);
                acc = __builtin_amdgcn_mfma_f32_16x16x32_bf16(af, bf, acc, 0, 0, 0);
            }
            int ch = wn * 16 + m;
            float bb = b1s[ch];
#pragma unroll
            for (int r = 0; r < 4; ++r) {
                int node = wr * 16 + quad * 4 + r;
                H1T[ch * 266 + node] = f2bbits(fmaxf(acc[r] + bb, 0.f));
            }
        }
        __syncthreads();                                  // B6

        // ---- P3: zero Ms; build M(h1) rows 128..255 (8 thr/row)
        {
            uint4* mz = (uint4*)Ms;
            uint4 z = {0u, 0u, 0u, 0u};
            for (int i = t; i < 4096; i += TPB) mz[i] = z;
        }
        __syncthreads();                                  // B7
        {
            int dl = t >> 3, q = t & 7;
            int d = 128 + dl;
            float did = dinvs[d];
            int sd = d & 255;
            if ((sd >> 5) == q) {
                *(unsigned short*)(Ms + dl * 512 + (((sd >> 3) ^ (d & 15)) * 16) + (sd & 7) * 2)
                    = f2bbits(did * did);
            }
            int r0 = Rl[d], r1 = Rl[d + 1];
            for (int e = r0; e < r1; ++e) {
                int s = El[e];
                if ((s >> 5) == q) {
                    unsigned short* p =
                        (unsigned short*)(Ms + dl * 512 + (((s >> 3) ^ (d & 15)) * 16) + (s & 7) * 2);
                    *p = f2bbits(bfbits(*p) + did * dinvs[s]);
                }
            }
        }
        __syncthreads();                                  // B8

        // ---- P4: agg1(h1) -> H1T nodes 128..255
        {
            f32x4 acc = {};
            for (int kt = 0; kt < 8; ++kt) {
                short8 af = *(const short8*)(Ms + (wr * 16 + m) * 512 + (((kt * 4 + quad) ^ m) * 16));
                short8 bf = *(const short8*)(BufA + (size_t)(wn * 16 + m) * 532 + kt * 64 + quad * 16);
                acc = __builtin_amdgcn_mfma_f32_16x16x32_bf16(af, bf, acc, 0, 0, 0);
            }
            int ch = wn * 16 + m;
            float bb = b1s[ch];
#pragma unroll
            for (int r = 0; r < 4; ++r) {
                int node = 128 + wr * 16 + quad * 4 + r;
                H1T[ch * 266 + node] = f2bbits(fmaxf(acc[r] + bb, 0.f));
            }
        }
        __syncthreads();                                  // B9

        // ---- P5: agg2'(h1) [M(h1) resident] -> S2 rows 128..255
        {
            f32x4 acc = {};
            for (int kt = 0; kt < 8; ++kt) {
                short8 af = *(const short8*)(Ms + (wr * 16 + m) * 512 + (((kt * 4 + quad) ^ m) * 16));
                short8 bf = *(const short8*)(BufB + (size_t)(wn * 16 + m) * 532 + kt * 64 + quad * 16);
                acc = __builtin_amdgcn_mfma_f32_16x16x32_bf16(af, bf, acc, 0, 0, 0);
            }
            int ch = wn * 16 + m;
#pragma unroll
            for (int r = 0; r < 4; ++r) {
                int node = 128 + wr * 16 + quad * 4 + r;
                S2[node * 38 + ch] = f2bbits(acc[r]);
            }
        }
        __syncthreads();                                  // B10

        // ---- P6: zero Ms; rebuild M(h0) rows 0..127 (8 thr/row)
        {
            uint4* mz = (uint4*)Ms;
            uint4 z = {0u, 0u, 0u, 0u};
            for (int i = t; i < 4096; i += TPB) mz[i] = z;
        }
        __syncthreads();                                  // B11
        {
            int dl = t >> 3, q = t & 7;
            int d = dl;
            float did = dinvs[d];
            if ((d >> 5) == q)
                *(unsigned short*)(Ms + dl * 512 + (((d >> 3) ^ (d & 15)) * 16) + (d & 7) * 2)
                    = f2bbits(did * did);
            int r0 = Rl[d], r1 = Rl[d + 1];
            for (int e = r0; e < r1; ++e) {
                int s = El[e];
                if ((s >> 5) == q) {
                    unsigned short* p =
                        (unsigned short*)(Ms + dl * 512 + (((s >> 3) ^ (d & 15)) * 16) + (s & 7) * 2);
                    *p = f2bbits(bfbits(*p) + did * dinvs[s]);
                }
            }
        }
        __syncthreads();                                  // B12

        // ---- P7: agg2'(h0) -> S2 rows 0..127
        {
            f32x4 acc = {};
            for (int kt = 0; kt < 8; ++kt) {
                short8 af = *(const short8*)(Ms + (wr * 16 + m) * 512 + (((kt * 4 + quad) ^ m) * 16));
                short8 bf = *(const short8*)(BufB + (size_t)(wn * 16 + m) * 532 + kt * 64 + quad * 16);
                acc = __builtin_amdgcn_mfma_f32_16x16x32_bf16(af, bf, acc, 0, 0, 0);
            }
            int ch = wn * 16 + m;
#pragma unroll
            for (int r = 0; r < 4; ++r) {
                int node = wr * 16 + quad * 4 + r;
                S2[node * 38 + ch] = f2bbits(acc[r]);
            }
        }
        __syncthreads();                                  // B13

        // ---- P8: lin2 = relu(S2@W2+b2); pool + stations (1 M-tile/wave)
        {
            int mt = wvid;
            short8 af = *(const short8*)(BufC + (size_t)(mt * 16 + m) * 76 + quad * 16);
#pragma unroll
            for (int ni = 0; ni < 4; ++ni) {
                short8 bf = *(const short8*)((const unsigned char*)W2Ts + (size_t)(ni * 16 + m) * 80 + quad * 16);
                f32x4 c = {};
                c = __builtin_amdgcn_mfma_f32_16x16x32_bf16(af, bf, c, 0, 0, 0);
                int ch = ni * 16 + m;
                float bb = b2s[ch];
                float hv[4];
                float p = 0.f;
#pragma unroll
                for (int r = 0; r < 4; ++r) { hv[r] = fmaxf(c[r] + bb, 0.f); p += hv[r]; }
                p += __shfl_down(p, 32);
                p += __shfl_down(p, 16);
                if (quad == 0) atomicAdd(&poolf[ch], p);
#pragma unroll
                for (int r = 0; r < 4; ++r) {
                    int node = mt * 16 + quad * 4 + r;
                    int si = stmap[node];
                    if (si != 255) sts[si * 64 + ch] = hv[r];
                }
            }
        }
        __syncthreads();                                  // B14

        // ---- P9: mean
        if (t < 64) meanf[t] = poolf[t] * (1.0f / 256.0f);
        __syncthreads();                                  // B15

        // ---- P10: MLP, one wave per station (waves 8..15 idle)
        if (wvid < 8) {
            int l = lane;
            int si = wvid;
            const float* st = sts + si * 64;
            float acc = 0.f;
#pragma unroll 8
            for (int k = 0; k < 64; k++) acc += st[k] * bfbits(fc1s16[k * 64 + l]);
#pragma unroll 8
            for (int k = 0; k < 64; k++) acc += meanf[k] * bfbits(fc1s16[(64 + k) * 64 + l]);
            float a = fmaxf(acc + fc1bs[l], 0.f) * fc2ws[l];
            for (int off = 32; off > 0; off >>= 1) a += __shfl_down(a, off);
            if (l == 0) out[g * 8 + si] = a + fc2bv;
        }
        __syncthreads();                                  // B16 (loop hazard fence)
    }
}

// ---- launch -----------------------------------------------------------------

extern "C" void kernel_launch(void* const* d_in, const int* in_sizes, int n_in,
                              void* d_out, int out_size, void* d_ws, size_t ws_size,
                              hipStream_t stream) {
    const float* x = (const float*)d_in[0];
    const int* ei = (const int*)d_in[1];
    const int* station_ids = (const int*)d_in[2];
    const float* W1 = (const float*)d_in[3];
    const float* b1 = (const float*)d_in[4];
    const float* W2 = (const float*)d_in[5];
    const float* bias2 = (const float*)d_in[6];
    const float* fc1W = (const float*)d_in[7];
    const float* fc1b = (const float*)d_in[8];
    const float* fc2W = (const float*)d_in[9];
    const float* fc2b = (const float*)d_in[10];
    float* out = (float*)d_out;
    (void)in_sizes; (void)n_in; (void)out_size; (void)ws_size;

    char* ws = (char*)d_ws;
    int* gcnt = (int*)ws;                                     // 64 KiB, stride-16 totals
    unsigned short* gout = (unsigned short*)(ws + 0x10000);   // 5.24 MB
    int* hist = (int*)(ws + 0x510000);                        // 1 MB: [tile][graph]

    const int* esrc = ei;
    const int* edst = ei + NEDGES;

    k_hist<<<NTILES, 1024, 0, stream>>>(edst, hist);
    k_scan<<<NGRAPHS, 256, 0, stream>>>(hist, gcnt);
    k_scatter<<<NTILES, 1024, 0, stream>>>(esrc, edst, hist, gout);
    k_fused<<<NBLK, TPB, 0, stream>>>(x, station_ids, W1, b1, W2, bias2,
                                      fc1W, fc1b, fc2W, fc2b, gcnt, gout, out);
}

// Round 4
// 172.828 us; speedup vs baseline: 1.1616x; 1.0880x over previous
//
#include <hip/hip_runtime.h>
#include <hip/hip_bf16.h>

// GraphQNetwork: 2x GCNConv (9->32->64, relu) + global mean pool + station MLP.
// Round 17: k_fused restructured around a FULL resident 256x256 bf16 M
// (128 KB LDS). M built once per graph (was 3 half-builds + 3 zero phases):
// build self-zeros via the q<->half-row mapping of the XOR swizzle. agg1 is
// held in registers (G1T/H1T share one swizzled 16 KB buffer); agg2 output is
// written into each wave's own dead Ms rows (no S2 buffer); W2 fragments are
// persistent in registers; fc1^T staged per-graph into dead Ms upper halves
// and the station MLP is one 16-MFMA wave. 11 barriers/graph (was 16).
// Partition kernels (hist/scan/scatter) unchanged.

#define NNODES 262144
#define NPG 256
#define NGRAPHS 1024
#define NEDGES 2097152
#define NFEAT 9
#define ECAP2 2560
#define T_EDGES 8192
#define NTILES (NEDGES / T_EDGES)   // 256
#define TPB 1024
#define NBLK 256

typedef __hip_bfloat16 bf16;
typedef short short8 __attribute__((ext_vector_type(8)));
typedef float f32x4 __attribute__((ext_vector_type(4)));

__device__ __forceinline__ float bfbits(unsigned short u) { return __uint_as_float(((unsigned)u) << 16); }
__device__ __forceinline__ unsigned short f2bbits(float v) { bf16 b = __float2bfloat16(v); return *(unsigned short*)&b; }

// ---- edge partition: deterministic counting sort, no global atomics --------

__global__ void __launch_bounds__(1024) k_hist(const int* __restrict__ dst,
                                               int* __restrict__ hist) {
    __shared__ int cnt[NGRAPHS];
    int t = threadIdx.x;
    cnt[t] = 0;
    __syncthreads();
    const int4* d4 = (const int4*)(dst + blockIdx.x * T_EDGES);
#pragma unroll
    for (int k = 0; k < T_EDGES / 4096; ++k) {
        int4 dv = d4[k * 1024 + t];
        atomicAdd(&cnt[dv.x >> 8], 1);
        atomicAdd(&cnt[dv.y >> 8], 1);
        atomicAdd(&cnt[dv.z >> 8], 1);
        atomicAdd(&cnt[dv.w >> 8], 1);
    }
    __syncthreads();
    hist[blockIdx.x * NGRAPHS + t] = cnt[t];
}

__global__ void __launch_bounds__(256) k_scan(int* __restrict__ hist,
                                              int* __restrict__ gcnt) {
    __shared__ int wsum[4];
    int g = blockIdx.x;
    int t = threadIdx.x;            // tile index
    int lane = t & 63, wv = t >> 6;
    int v = hist[t * NGRAPHS + g];
    int inc = v;
    for (int off = 1; off < 64; off <<= 1) {
        int y = __shfl_up(inc, off);
        if (lane >= off) inc += y;
    }
    if (lane == 63) wsum[wv] = inc;
    __syncthreads();
    int wpre = 0;
#pragma unroll
    for (int w = 0; w < 3; ++w) if (w < wv) wpre += wsum[w];
    int exc = wpre + inc - v;
    hist[t * NGRAPHS + g] = exc;
    if (t == 255) gcnt[g * 16] = exc + v;
}

__global__ void __launch_bounds__(1024) k_scatter(const int* __restrict__ src,
                                                  const int* __restrict__ dst,
                                                  const int* __restrict__ hist,
                                                  unsigned short* __restrict__ gout) {
    __shared__ unsigned short sg[T_EDGES];
    __shared__ unsigned short pay[T_EDGES];
    __shared__ unsigned short spay[T_EDGES];
    __shared__ unsigned short ssg[T_EDGES];
    __shared__ int cnt[NGRAPHS];
    __shared__ int lbase[NGRAPHS];
    __shared__ int gb[NGRAPHS];
    __shared__ int wsum[16];
    int t = threadIdx.x;
    int lane = t & 63, wv = t >> 6;
    int base = blockIdx.x * T_EDGES;
    cnt[t] = 0;
    gb[t] = hist[blockIdx.x * NGRAPHS + t];
    __syncthreads();
    const int4* s4 = (const int4*)(src + base);
    const int4* d4 = (const int4*)(dst + base);
#pragma unroll
    for (int k = 0; k < T_EDGES / 4096; ++k) {
        int idx = k * 1024 + t;
        int4 dv = d4[idx];
        int4 sv = s4[idx];
        int i0 = idx * 4;
        sg[i0]     = (unsigned short)(dv.x >> 8);
        sg[i0 + 1] = (unsigned short)(dv.y >> 8);
        sg[i0 + 2] = (unsigned short)(dv.z >> 8);
        sg[i0 + 3] = (unsigned short)(dv.w >> 8);
        pay[i0]     = (unsigned short)(((dv.x & 255) << 8) | (sv.x & 255));
        pay[i0 + 1] = (unsigned short)(((dv.y & 255) << 8) | (sv.y & 255));
        pay[i0 + 2] = (unsigned short)(((dv.z & 255) << 8) | (sv.z & 255));
        pay[i0 + 3] = (unsigned short)(((dv.w & 255) << 8) | (sv.w & 255));
        atomicAdd(&cnt[dv.x >> 8], 1);
        atomicAdd(&cnt[dv.y >> 8], 1);
        atomicAdd(&cnt[dv.z >> 8], 1);
        atomicAdd(&cnt[dv.w >> 8], 1);
    }
    __syncthreads();
    int c = cnt[t];
    int inc = c;
    for (int off = 1; off < 64; off <<= 1) {
        int y = __shfl_up(inc, off);
        if (lane >= off) inc += y;
    }
    if (lane == 63) wsum[wv] = inc;
    __syncthreads();
    int wpre = 0;
    for (int w = 0; w < wv; ++w) wpre += wsum[w];
    lbase[t] = wpre + inc - c;
    cnt[t] = 0;
    __syncthreads();
#pragma unroll
    for (int k = 0; k < T_EDGES / 1024; ++k) {
        int i = k * 1024 + t;
        int g = sg[i];
        int p = lbase[g] + atomicAdd(&cnt[g], 1);
        spay[p] = pay[i];
        ssg[p] = (unsigned short)g;
    }
    __syncthreads();
#pragma unroll
    for (int k = 0; k < T_EDGES / 1024; ++k) {
        int p = k * 1024 + t;
        int g = ssg[p];
        int off = gb[g] + (p - lbase[g]);
        if (off < ECAP2) gout[(size_t)g * ECAP2 + off] = spay[p];
    }
}

// ---- persistent fused kernel: full resident M, 16 waves --------------------

__global__ void __launch_bounds__(TPB) k_fused(
    const float* __restrict__ x, const int* __restrict__ station_ids,
    const float* __restrict__ W1, const float* __restrict__ b1,
    const float* __restrict__ W2, const float* __restrict__ b2,
    const float* __restrict__ fc1W, const float* __restrict__ fc1b,
    const float* __restrict__ fc2W, const float* __restrict__ fc2b,
    const int* __restrict__ gcnt, const unsigned short* __restrict__ gedges,
    float* __restrict__ out) {

    __shared__ __align__(16) unsigned char Ms[131072];   // full M: 256 x 512 B
    __shared__ __align__(16) unsigned char Buf[16384];   // G1T then H1T [32][256] swz
    __shared__ __align__(16) unsigned short EPa[ECAP2];  // 5120 B
    __shared__ unsigned char El[ECAP2];                  // 2560 B
    __shared__ unsigned int sru[256];                    // hist -> cursors
    __shared__ unsigned short Rl[260];
    __shared__ float dinvs[256];
    __shared__ float W1s[288];
    __shared__ float sts[512];                           // [8][64] f32
    __shared__ float poolf[64];
    __shared__ float meanf[64];
    __shared__ unsigned char stmap[256];
    __shared__ float b1s[32], b2s[64], fc1bs[64], fc2ws[64];
    __shared__ int stids[8];
    __shared__ float fc2bv;

    int t = threadIdx.x;
    int lane = t & 63, wvid = t >> 6;                    // 16 waves
    int m = lane & 15, quad = lane >> 4;

    // ---- persistent staging (once per block) ----
    for (int i = t; i < NFEAT * 32; i += TPB) W1s[i] = W1[i];
    if (t < 32) b1s[t] = b1[t];
    if (t < 64) { b2s[t] = b2[t]; fc1bs[t] = fc1b[t]; fc2ws[t] = fc2W[t]; }
    if (t < 8) stids[t] = station_ids[t];
    if (t == 0) fc2bv = fc2b[0];
    if (t < 256) stmap[t] = 255;
    // W2 B-fragments, persistent in registers: w2f[ni] = W2[quad*8+j][ni*16+m]
    short8 w2f[4];
#pragma unroll
    for (int ni = 0; ni < 4; ++ni)
#pragma unroll
        for (int j = 0; j < 8; ++j)
            w2f[ni][j] = (short)f2bbits(W2[(quad * 8 + j) * 64 + ni * 16 + m]);
    __syncthreads();
    if (t < 8) stmap[stids[t] & 255] = (unsigned char)t;

    for (int g = blockIdx.x; g < NGRAPHS; g += NBLK) {

        // ---- P0: stage EPa; zero hist + pool
        int ecnt = min(gcnt[g * 16], ECAP2);
        {
            const uint4* gev = (const uint4*)(gedges + (size_t)g * ECAP2);
            uint4* epv = (uint4*)EPa;
            for (int i = t; i < ECAP2 / 8; i += TPB) epv[i] = gev[i];
        }
        if (t < 256) sru[t] = 0u;
        if (t >= 256 && t < 320) poolf[t - 256] = 0.f;
        __syncthreads();                                  // B1

        // ---- P0b: dst histogram
        for (int i = t; i < ecnt; i += TPB) atomicAdd(&sru[EPa[i] >> 8], 1u);
        __syncthreads();                                  // B2

        // ---- P0c: single-wave scan -> Rl, cursors (overwrite sru), dinvs
        if (wvid == 0) {
            int b0 = sru[lane * 4], b1v = sru[lane * 4 + 1];
            int b2v = sru[lane * 4 + 2], b3 = sru[lane * 4 + 3];
            int s = b0 + b1v + b2v + b3;
            int inc = s;
            for (int off = 1; off < 64; off <<= 1) {
                int y = __shfl_up(inc, off);
                if (lane >= off) inc += y;
            }
            int r0 = inc - s;
            int r1 = r0 + b0, r2 = r1 + b1v, r3 = r2 + b2v;
            Rl[lane * 4] = (unsigned short)r0;     dinvs[lane * 4] = rsqrtf((float)(b0 + 1));
            Rl[lane * 4 + 1] = (unsigned short)r1; dinvs[lane * 4 + 1] = rsqrtf((float)(b1v + 1));
            Rl[lane * 4 + 2] = (unsigned short)r2; dinvs[lane * 4 + 2] = rsqrtf((float)(b2v + 1));
            Rl[lane * 4 + 3] = (unsigned short)r3; dinvs[lane * 4 + 3] = rsqrtf((float)(b3 + 1));
            sru[lane * 4] = r0; sru[lane * 4 + 1] = r1;
            sru[lane * 4 + 2] = r2; sru[lane * 4 + 3] = r3;
            if (lane == 63) Rl[256] = (unsigned short)inc;
        }
        __syncthreads();                                  // B3

        // ---- P0d: scatter -> El
        for (int i = t; i < ecnt; i += TPB) {
            unsigned short v = EPa[i];
            unsigned p = atomicAdd(&sru[v >> 8], 1u);
            if (p < ECAP2) El[p] = (unsigned char)(v & 255);
        }
        __syncthreads();                                  // B4

        // ---- P1: t<512 full M-build (2 thr/row, self-zeroing) ; t>=512 lin1
        if (t < 512) {
            int d = t >> 1, q = t & 1;
            // q=0 owns s<128 -> chunks 0..15 (bytes [0,256)); q=1 owns [256,512)
            uint4* mz = (uint4*)(Ms + d * 512 + q * 256);
            uint4 z = {0u, 0u, 0u, 0u};
#pragma unroll
            for (int i = 0; i < 16; ++i) mz[i] = z;
            float did = dinvs[d];
            if ((d >> 7) == q)
                *(unsigned short*)(Ms + d * 512 + (((d >> 3) ^ (d & 15)) * 16) + (d & 7) * 2)
                    = f2bbits(did * did);
            int r0 = Rl[d], r1 = Rl[d + 1];
            for (int e = r0; e < r1; ++e) {
                int s = El[e];
                if ((s >> 7) == q) {
                    unsigned short* p =
                        (unsigned short*)(Ms + d * 512 + (((s >> 3) ^ (d & 15)) * 16) + (s & 7) * 2);
                    *p = f2bbits(bfbits(*p) + did * dinvs[s]);
                }
            }
        } else {
            int tt = t - 512;
            int n = tt >> 1, half = tt & 1;
            const float* xr = x + (size_t)(g * NPG + n) * NFEAT;
            float xv[NFEAT];
#pragma unroll
            for (int k = 0; k < NFEAT; ++k) xv[k] = xr[k];
            int c0 = half * 16;
#pragma unroll 4
            for (int ci = 0; ci < 16; ++ci) {
                int c = c0 + ci;
                float acc = 0.f;
#pragma unroll
                for (int k = 0; k < NFEAT; ++k) acc += xv[k] * W1s[k * 32 + c];
                *(unsigned short*)(Buf + c * 512 + (((n >> 3) ^ (c & 15)) * 16) + (n & 7) * 2)
                    = f2bbits(acc);
            }
        }
        __syncthreads();                                  // B5

        // ---- P2: agg1 full -> registers (wave = 16-node row tile, 2 ch tiles)
        f32x4 acc1[2] = {};
        for (int kt = 0; kt < 8; ++kt) {
            short8 af = *(const short8*)(Ms + (size_t)(wvid * 16 + m) * 512 + (((kt * 4 + quad) ^ m) * 16));
            short8 bf0 = *(const short8*)(Buf + (size_t)m * 512 + (((kt * 4 + quad) ^ m) * 16));
            short8 bf1 = *(const short8*)(Buf + (size_t)(16 + m) * 512 + (((kt * 4 + quad) ^ m) * 16));
            acc1[0] = __builtin_amdgcn_mfma_f32_16x16x32_bf16(af, bf0, acc1[0], 0, 0, 0);
            acc1[1] = __builtin_amdgcn_mfma_f32_16x16x32_bf16(af, bf1, acc1[1], 0, 0, 0);
        }
        __syncthreads();                                  // B6 (all G1T reads done)

        // ---- P2b: relu+bias -> H1T over Buf
#pragma unroll
        for (int ct = 0; ct < 2; ++ct) {
            int ch = ct * 16 + m;
            float bb = b1s[ch];
#pragma unroll
            for (int r = 0; r < 4; ++r) {
                int node = wvid * 16 + quad * 4 + r;
                *(unsigned short*)(Buf + (size_t)ch * 512 + (((node >> 3) ^ (ch & 15)) * 16) + (node & 7) * 2)
                    = f2bbits(fmaxf(acc1[ct][r] + bb, 0.f));
            }
        }
        __syncthreads();                                  // B7

        // ---- P3: agg2 (M resident) -> S2 slots in own dead Ms rows
        {
            f32x4 a2[2] = {};
            for (int kt = 0; kt < 8; ++kt) {
                short8 af = *(const short8*)(Ms + (size_t)(wvid * 16 + m) * 512 + (((kt * 4 + quad) ^ m) * 16));
                short8 bf0 = *(const short8*)(Buf + (size_t)m * 512 + (((kt * 4 + quad) ^ m) * 16));
                short8 bf1 = *(const short8*)(Buf + (size_t)(16 + m) * 512 + (((kt * 4 + quad) ^ m) * 16));
                a2[0] = __builtin_amdgcn_mfma_f32_16x16x32_bf16(af, bf0, a2[0], 0, 0, 0);
                a2[1] = __builtin_amdgcn_mfma_f32_16x16x32_bf16(af, bf1, a2[1], 0, 0, 0);
            }
            // wave wvid's output nodes == its own af rows: safe to overwrite
#pragma unroll
            for (int ct = 0; ct < 2; ++ct) {
                int ch = ct * 16 + m;
                int c8 = ch >> 3;
#pragma unroll
                for (int r = 0; r < 4; ++r) {
                    int node = wvid * 16 + quad * 4 + r;
                    *(unsigned short*)(Ms + (size_t)node * 512 + ((c8 ^ (node & 3)) * 16) + (ch & 7) * 2)
                        = f2bbits(a2[ct][r]);
                }
            }
        }
        __syncthreads();                                  // B8

        // ---- P4: fc1^T staging into dead Ms upper halves + lin2/pool/stations
        for (int i = t; i < 8192; i += TPB) {
            int k = i >> 6, c2 = i & 63;
            *(unsigned short*)(Ms + (size_t)c2 * 512 + 256 + (((k >> 3) ^ (c2 & 15)) * 16) + (k & 7) * 2)
                = f2bbits(fc1W[i]);
        }
        {
            int mt = wvid;
            short8 af = *(const short8*)(Ms + (size_t)(mt * 16 + m) * 512 + ((quad ^ (m & 3)) * 16));
#pragma unroll
            for (int ni = 0; ni < 4; ++ni) {
                f32x4 c = {};
                c = __builtin_amdgcn_mfma_f32_16x16x32_bf16(af, w2f[ni], c, 0, 0, 0);
                int ch = ni * 16 + m;
                float bb = b2s[ch];
                float hv[4];
                float p = 0.f;
#pragma unroll
                for (int r = 0; r < 4; ++r) { hv[r] = fmaxf(c[r] + bb, 0.f); p += hv[r]; }
                p += __shfl_down(p, 32);
                p += __shfl_down(p, 16);
                if (quad == 0) atomicAdd(&poolf[ch], p);
#pragma unroll
                for (int r = 0; r < 4; ++r) {
                    int node = mt * 16 + quad * 4 + r;
                    int si = stmap[node];
                    if (si != 255) sts[si * 64 + ch] = hv[r];
                }
            }
        }
        __syncthreads();                                  // B9

        // ---- P5: mean
        if (t < 64) meanf[t] = poolf[t] * (1.0f / 256.0f);
        __syncthreads();                                  // B10

        // ---- P6: station MLP as one-wave MFMA (M=16 rows: 8 stations + pad)
        if (wvid == 0) {
            short8 af4[4];
#pragma unroll
            for (int kt = 0; kt < 4; ++kt) {
#pragma unroll
                for (int j = 0; j < 8; ++j) {
                    int k = kt * 32 + quad * 8 + j;
                    float v = (m < 8) ? (k < 64 ? sts[m * 64 + k] : meanf[k - 64]) : 0.f;
                    af4[kt][j] = (short)f2bbits(v);
                }
            }
            f32x4 cc[4];
#pragma unroll
            for (int ni = 0; ni < 4; ++ni) {
                f32x4 c = {};
#pragma unroll
                for (int kt = 0; kt < 4; ++kt) {
                    short8 bf = *(const short8*)(Ms + (size_t)(ni * 16 + m) * 512 + 256 + (((kt * 4 + quad) ^ m) * 16));
                    c = __builtin_amdgcn_mfma_f32_16x16x32_bf16(af4[kt], bf, c, 0, 0, 0);
                }
                cc[ni] = c;
            }
#pragma unroll
            for (int r = 0; r < 4; ++r) {
                float a = 0.f;
#pragma unroll
                for (int ni = 0; ni < 4; ++ni)
                    a += fmaxf(cc[ni][r] + fc1bs[ni * 16 + m], 0.f) * fc2ws[ni * 16 + m];
#pragma unroll
                for (int off = 1; off < 16; off <<= 1) a += __shfl_xor(a, off);
                int st = quad * 4 + r;
                if (m == 0 && st < 8) out[g * 8 + st] = a + fc2bv;
            }
        }
        __syncthreads();                                  // B11 (loop fence)
    }
}

// ---- launch -----------------------------------------------------------------

extern "C" void kernel_launch(void* const* d_in, const int* in_sizes, int n_in,
                              void* d_out, int out_size, void* d_ws, size_t ws_size,
                              hipStream_t stream) {
    const float* x = (const float*)d_in[0];
    const int* ei = (const int*)d_in[1];
    const int* station_ids = (const int*)d_in[2];
    const float* W1 = (const float*)d_in[3];
    const float* b1 = (const float*)d_in[4];
    const float* W2 = (const float*)d_in[5];
    const float* bias2 = (const float*)d_in[6];
    const float* fc1W = (const float*)d_in[7];
    const float* fc1b = (const float*)d_in[8];
    const float* fc2W = (const float*)d_in[9];
    const float* fc2b = (const float*)d_in[10];
    float* out = (float*)d_out;
    (void)in_sizes; (void)n_in; (void)out_size; (void)ws_size;

    char* ws = (char*)d_ws;
    int* gcnt = (int*)ws;                                     // 64 KiB, stride-16 totals
    unsigned short* gout = (unsigned short*)(ws + 0x10000);   // 5.24 MB
    int* hist = (int*)(ws + 0x510000);                        // 1 MB: [tile][graph]

    const int* esrc = ei;
    const int* edst = ei + NEDGES;

    k_hist<<<NTILES, 1024, 0, stream>>>(edst, hist);
    k_scan<<<NGRAPHS, 256, 0, stream>>>(hist, gcnt);
    k_scatter<<<NTILES, 1024, 0, stream>>>(esrc, edst, hist, gout);
    k_fused<<<NBLK, TPB, 0, stream>>>(x, station_ids, W1, b1, W2, bias2,
                                      fc1W, fc1b, fc2W, fc2b, gcnt, gout, out);
}

// Round 5
// 166.509 us; speedup vs baseline: 1.2057x; 1.0380x over previous
//
#include <hip/hip_runtime.h>
#include <hip/hip_bf16.h>

// GraphQNetwork: 2x GCNConv (9->32->64, relu) + global mean pool + station MLP.
// Round 18: r17 minus the per-graph fc1^T LDS staging (it was a 64-way
// bank-conflict write pattern + 32KB global reads, every graph). fc1 B-frags
// now persistent in REGISTERS (fc1f[4] per thread, wave w holds channel block
// w&3); station MLP runs on waves 0..3 (4 MFMAs each, register-fed), partials
// combined via an 8-float LDS spart. meanf phase folded into the af4 build
// (poolf * 1/256). 10 barriers/graph. Partition kernels unchanged.

#define NNODES 262144
#define NPG 256
#define NGRAPHS 1024
#define NEDGES 2097152
#define NFEAT 9
#define ECAP2 2560
#define T_EDGES 8192
#define NTILES (NEDGES / T_EDGES)   // 256
#define TPB 1024
#define NBLK 256

typedef __hip_bfloat16 bf16;
typedef short short8 __attribute__((ext_vector_type(8)));
typedef float f32x4 __attribute__((ext_vector_type(4)));

__device__ __forceinline__ float bfbits(unsigned short u) { return __uint_as_float(((unsigned)u) << 16); }
__device__ __forceinline__ unsigned short f2bbits(float v) { bf16 b = __float2bfloat16(v); return *(unsigned short*)&b; }

// ---- edge partition: deterministic counting sort, no global atomics --------

__global__ void __launch_bounds__(1024) k_hist(const int* __restrict__ dst,
                                               int* __restrict__ hist) {
    __shared__ int cnt[NGRAPHS];
    int t = threadIdx.x;
    cnt[t] = 0;
    __syncthreads();
    const int4* d4 = (const int4*)(dst + blockIdx.x * T_EDGES);
#pragma unroll
    for (int k = 0; k < T_EDGES / 4096; ++k) {
        int4 dv = d4[k * 1024 + t];
        atomicAdd(&cnt[dv.x >> 8], 1);
        atomicAdd(&cnt[dv.y >> 8], 1);
        atomicAdd(&cnt[dv.z >> 8], 1);
        atomicAdd(&cnt[dv.w >> 8], 1);
    }
    __syncthreads();
    hist[blockIdx.x * NGRAPHS + t] = cnt[t];
}

__global__ void __launch_bounds__(256) k_scan(int* __restrict__ hist,
                                              int* __restrict__ gcnt) {
    __shared__ int wsum[4];
    int g = blockIdx.x;
    int t = threadIdx.x;            // tile index
    int lane = t & 63, wv = t >> 6;
    int v = hist[t * NGRAPHS + g];
    int inc = v;
    for (int off = 1; off < 64; off <<= 1) {
        int y = __shfl_up(inc, off);
        if (lane >= off) inc += y;
    }
    if (lane == 63) wsum[wv] = inc;
    __syncthreads();
    int wpre = 0;
#pragma unroll
    for (int w = 0; w < 3; ++w) if (w < wv) wpre += wsum[w];
    int exc = wpre + inc - v;
    hist[t * NGRAPHS + g] = exc;
    if (t == 255) gcnt[g * 16] = exc + v;
}

__global__ void __launch_bounds__(1024) k_scatter(const int* __restrict__ src,
                                                  const int* __restrict__ dst,
                                                  const int* __restrict__ hist,
                                                  unsigned short* __restrict__ gout) {
    __shared__ unsigned short sg[T_EDGES];
    __shared__ unsigned short pay[T_EDGES];
    __shared__ unsigned short spay[T_EDGES];
    __shared__ unsigned short ssg[T_EDGES];
    __shared__ int cnt[NGRAPHS];
    __shared__ int lbase[NGRAPHS];
    __shared__ int gb[NGRAPHS];
    __shared__ int wsum[16];
    int t = threadIdx.x;
    int lane = t & 63, wv = t >> 6;
    int base = blockIdx.x * T_EDGES;
    cnt[t] = 0;
    gb[t] = hist[blockIdx.x * NGRAPHS + t];
    __syncthreads();
    const int4* s4 = (const int4*)(src + base);
    const int4* d4 = (const int4*)(dst + base);
#pragma unroll
    for (int k = 0; k < T_EDGES / 4096; ++k) {
        int idx = k * 1024 + t;
        int4 dv = d4[idx];
        int4 sv = s4[idx];
        int i0 = idx * 4;
        sg[i0]     = (unsigned short)(dv.x >> 8);
        sg[i0 + 1] = (unsigned short)(dv.y >> 8);
        sg[i0 + 2] = (unsigned short)(dv.z >> 8);
        sg[i0 + 3] = (unsigned short)(dv.w >> 8);
        pay[i0]     = (unsigned short)(((dv.x & 255) << 8) | (sv.x & 255));
        pay[i0 + 1] = (unsigned short)(((dv.y & 255) << 8) | (sv.y & 255));
        pay[i0 + 2] = (unsigned short)(((dv.z & 255) << 8) | (sv.z & 255));
        pay[i0 + 3] = (unsigned short)(((dv.w & 255) << 8) | (sv.w & 255));
        atomicAdd(&cnt[dv.x >> 8], 1);
        atomicAdd(&cnt[dv.y >> 8], 1);
        atomicAdd(&cnt[dv.z >> 8], 1);
        atomicAdd(&cnt[dv.w >> 8], 1);
    }
    __syncthreads();
    int c = cnt[t];
    int inc = c;
    for (int off = 1; off < 64; off <<= 1) {
        int y = __shfl_up(inc, off);
        if (lane >= off) inc += y;
    }
    if (lane == 63) wsum[wv] = inc;
    __syncthreads();
    int wpre = 0;
    for (int w = 0; w < wv; ++w) wpre += wsum[w];
    lbase[t] = wpre + inc - c;
    cnt[t] = 0;
    __syncthreads();
#pragma unroll
    for (int k = 0; k < T_EDGES / 1024; ++k) {
        int i = k * 1024 + t;
        int g = sg[i];
        int p = lbase[g] + atomicAdd(&cnt[g], 1);
        spay[p] = pay[i];
        ssg[p] = (unsigned short)g;
    }
    __syncthreads();
#pragma unroll
    for (int k = 0; k < T_EDGES / 1024; ++k) {
        int p = k * 1024 + t;
        int g = ssg[p];
        int off = gb[g] + (p - lbase[g]);
        if (off < ECAP2) gout[(size_t)g * ECAP2 + off] = spay[p];
    }
}

// ---- persistent fused kernel: full resident M, 16 waves --------------------

__global__ void __launch_bounds__(TPB) k_fused(
    const float* __restrict__ x, const int* __restrict__ station_ids,
    const float* __restrict__ W1, const float* __restrict__ b1,
    const float* __restrict__ W2, const float* __restrict__ b2,
    const float* __restrict__ fc1W, const float* __restrict__ fc1b,
    const float* __restrict__ fc2W, const float* __restrict__ fc2b,
    const int* __restrict__ gcnt, const unsigned short* __restrict__ gedges,
    float* __restrict__ out) {

    __shared__ __align__(16) unsigned char Ms[131072];   // full M: 256 x 512 B
    __shared__ __align__(16) unsigned char Buf[16384];   // G1T then H1T [32][256] swz
    __shared__ __align__(16) unsigned short EPa[ECAP2];  // 5120 B
    __shared__ unsigned char El[ECAP2];                  // 2560 B
    __shared__ unsigned int sru[256];                    // hist -> cursors
    __shared__ unsigned short Rl[260];
    __shared__ float dinvs[256];
    __shared__ float W1s[288];
    __shared__ float sts[512];                           // [8][64] f32
    __shared__ float poolf[64];
    __shared__ float spart[8];
    __shared__ unsigned char stmap[256];
    __shared__ float b1s[32], b2s[64], fc1bs[64], fc2ws[64];
    __shared__ int stids[8];
    __shared__ float fc2bv;

    int t = threadIdx.x;
    int lane = t & 63, wvid = t >> 6;                    // 16 waves
    int m = lane & 15, quad = lane >> 4;

    // ---- persistent staging (once per block) ----
    for (int i = t; i < NFEAT * 32; i += TPB) W1s[i] = W1[i];
    if (t < 32) b1s[t] = b1[t];
    if (t < 64) { b2s[t] = b2[t]; fc1bs[t] = fc1b[t]; fc2ws[t] = fc2W[t]; }
    if (t < 8) { stids[t] = station_ids[t]; spart[t] = 0.f; }
    if (t == 0) fc2bv = fc2b[0];
    if (t < 256) stmap[t] = 255;
    // W2 B-fragments, persistent in registers: w2f[ni] = W2[quad*8+j][ni*16+m]
    short8 w2f[4];
#pragma unroll
    for (int ni = 0; ni < 4; ++ni)
#pragma unroll
        for (int j = 0; j < 8; ++j)
            w2f[ni][j] = (short)f2bbits(W2[(quad * 8 + j) * 64 + ni * 16 + m]);
    // fc1 B-fragments, persistent in registers: wave w holds channel block w&3.
    // fc1f[kt][j] = fc1[(kt*4+quad)*8+j][(wvid&3)*16+m]
    short8 fc1f[4];
    {
        int ni = wvid & 3;
#pragma unroll
        for (int kt = 0; kt < 4; ++kt)
#pragma unroll
            for (int j = 0; j < 8; ++j)
                fc1f[kt][j] = (short)f2bbits(fc1W[((kt * 4 + quad) * 8 + j) * 64 + ni * 16 + m]);
    }
    __syncthreads();
    if (t < 8) stmap[stids[t] & 255] = (unsigned char)t;

    for (int g = blockIdx.x; g < NGRAPHS; g += NBLK) {

        // ---- P0: stage EPa; zero hist + pool
        int ecnt = min(gcnt[g * 16], ECAP2);
        {
            const uint4* gev = (const uint4*)(gedges + (size_t)g * ECAP2);
            uint4* epv = (uint4*)EPa;
            for (int i = t; i < ECAP2 / 8; i += TPB) epv[i] = gev[i];
        }
        if (t < 256) sru[t] = 0u;
        if (t >= 256 && t < 320) poolf[t - 256] = 0.f;
        __syncthreads();                                  // B1

        // ---- P0b: dst histogram (+ spart re-zero)
        if (t < 8) spart[t] = 0.f;
        for (int i = t; i < ecnt; i += TPB) atomicAdd(&sru[EPa[i] >> 8], 1u);
        __syncthreads();                                  // B2

        // ---- P0c: single-wave scan -> Rl, cursors (overwrite sru), dinvs
        if (wvid == 0) {
            int b0 = sru[lane * 4], b1v = sru[lane * 4 + 1];
            int b2v = sru[lane * 4 + 2], b3 = sru[lane * 4 + 3];
            int s = b0 + b1v + b2v + b3;
            int inc = s;
            for (int off = 1; off < 64; off <<= 1) {
                int y = __shfl_up(inc, off);
                if (lane >= off) inc += y;
            }
            int r0 = inc - s;
            int r1 = r0 + b0, r2 = r1 + b1v, r3 = r2 + b2v;
            Rl[lane * 4] = (unsigned short)r0;     dinvs[lane * 4] = rsqrtf((float)(b0 + 1));
            Rl[lane * 4 + 1] = (unsigned short)r1; dinvs[lane * 4 + 1] = rsqrtf((float)(b1v + 1));
            Rl[lane * 4 + 2] = (unsigned short)r2; dinvs[lane * 4 + 2] = rsqrtf((float)(b2v + 1));
            Rl[lane * 4 + 3] = (unsigned short)r3; dinvs[lane * 4 + 3] = rsqrtf((float)(b3 + 1));
            sru[lane * 4] = r0; sru[lane * 4 + 1] = r1;
            sru[lane * 4 + 2] = r2; sru[lane * 4 + 3] = r3;
            if (lane == 63) Rl[256] = (unsigned short)inc;
        }
        __syncthreads();                                  // B3

        // ---- P0d: scatter -> El
        for (int i = t; i < ecnt; i += TPB) {
            unsigned short v = EPa[i];
            unsigned p = atomicAdd(&sru[v >> 8], 1u);
            if (p < ECAP2) El[p] = (unsigned char)(v & 255);
        }
        __syncthreads();                                  // B4

        // ---- P1: t<512 full M-build (2 thr/row, self-zeroing) ; t>=512 lin1
        if (t < 512) {
            int d = t >> 1, q = t & 1;
            uint4* mz = (uint4*)(Ms + d * 512 + q * 256);
            uint4 z = {0u, 0u, 0u, 0u};
#pragma unroll
            for (int i = 0; i < 16; ++i) mz[i] = z;
            float did = dinvs[d];
            if ((d >> 7) == q)
                *(unsigned short*)(Ms + d * 512 + (((d >> 3) ^ (d & 15)) * 16) + (d & 7) * 2)
                    = f2bbits(did * did);
            int r0 = Rl[d], r1 = Rl[d + 1];
            for (int e = r0; e < r1; ++e) {
                int s = El[e];
                if ((s >> 7) == q) {
                    unsigned short* p =
                        (unsigned short*)(Ms + d * 512 + (((s >> 3) ^ (d & 15)) * 16) + (s & 7) * 2);
                    *p = f2bbits(bfbits(*p) + did * dinvs[s]);
                }
            }
        } else {
            int tt = t - 512;
            int n = tt >> 1, half = tt & 1;
            const float* xr = x + (size_t)(g * NPG + n) * NFEAT;
            float xv[NFEAT];
#pragma unroll
            for (int k = 0; k < NFEAT; ++k) xv[k] = xr[k];
            int c0 = half * 16;
#pragma unroll 4
            for (int ci = 0; ci < 16; ++ci) {
                int c = c0 + ci;
                float acc = 0.f;
#pragma unroll
                for (int k = 0; k < NFEAT; ++k) acc += xv[k] * W1s[k * 32 + c];
                *(unsigned short*)(Buf + c * 512 + (((n >> 3) ^ (c & 15)) * 16) + (n & 7) * 2)
                    = f2bbits(acc);
            }
        }
        __syncthreads();                                  // B5

        // ---- P2: agg1 full -> registers (wave = 16-node row tile, 2 ch tiles)
        f32x4 acc1[2] = {};
        for (int kt = 0; kt < 8; ++kt) {
            short8 af = *(const short8*)(Ms + (size_t)(wvid * 16 + m) * 512 + (((kt * 4 + quad) ^ m) * 16));
            short8 bf0 = *(const short8*)(Buf + (size_t)m * 512 + (((kt * 4 + quad) ^ m) * 16));
            short8 bf1 = *(const short8*)(Buf + (size_t)(16 + m) * 512 + (((kt * 4 + quad) ^ m) * 16));
            acc1[0] = __builtin_amdgcn_mfma_f32_16x16x32_bf16(af, bf0, acc1[0], 0, 0, 0);
            acc1[1] = __builtin_amdgcn_mfma_f32_16x16x32_bf16(af, bf1, acc1[1], 0, 0, 0);
        }
        __syncthreads();                                  // B6 (all G1T reads done)

        // ---- P2b: relu+bias -> H1T over Buf
#pragma unroll
        for (int ct = 0; ct < 2; ++ct) {
            int ch = ct * 16 + m;
            float bb = b1s[ch];
#pragma unroll
            for (int r = 0; r < 4; ++r) {
                int node = wvid * 16 + quad * 4 + r;
                *(unsigned short*)(Buf + (size_t)ch * 512 + (((node >> 3) ^ (ch & 15)) * 16) + (node & 7) * 2)
                    = f2bbits(fmaxf(acc1[ct][r] + bb, 0.f));
            }
        }
        __syncthreads();                                  // B7

        // ---- P3: agg2 (M resident) -> S2 slots in own dead Ms rows
        {
            f32x4 a2[2] = {};
            for (int kt = 0; kt < 8; ++kt) {
                short8 af = *(const short8*)(Ms + (size_t)(wvid * 16 + m) * 512 + (((kt * 4 + quad) ^ m) * 16));
                short8 bf0 = *(const short8*)(Buf + (size_t)m * 512 + (((kt * 4 + quad) ^ m) * 16));
                short8 bf1 = *(const short8*)(Buf + (size_t)(16 + m) * 512 + (((kt * 4 + quad) ^ m) * 16));
                a2[0] = __builtin_amdgcn_mfma_f32_16x16x32_bf16(af, bf0, a2[0], 0, 0, 0);
                a2[1] = __builtin_amdgcn_mfma_f32_16x16x32_bf16(af, bf1, a2[1], 0, 0, 0);
            }
            // wave wvid's output nodes == its own af rows: safe to overwrite
#pragma unroll
            for (int ct = 0; ct < 2; ++ct) {
                int ch = ct * 16 + m;
                int c8 = ch >> 3;
#pragma unroll
                for (int r = 0; r < 4; ++r) {
                    int node = wvid * 16 + quad * 4 + r;
                    *(unsigned short*)(Ms + (size_t)node * 512 + ((c8 ^ (node & 3)) * 16) + (ch & 7) * 2)
                        = f2bbits(a2[ct][r]);
                }
            }
        }
        __syncthreads();                                  // B8

        // ---- P4: lin2 = relu(S2@W2+b2); pool + stations (W2 in registers)
        {
            int mt = wvid;
            short8 af = *(const short8*)(Ms + (size_t)(mt * 16 + m) * 512 + ((quad ^ (m & 3)) * 16));
#pragma unroll
            for (int ni = 0; ni < 4; ++ni) {
                f32x4 c = {};
                c = __builtin_amdgcn_mfma_f32_16x16x32_bf16(af, w2f[ni], c, 0, 0, 0);
                int ch = ni * 16 + m;
                float bb = b2s[ch];
                float hv[4];
                float p = 0.f;
#pragma unroll
                for (int r = 0; r < 4; ++r) { hv[r] = fmaxf(c[r] + bb, 0.f); p += hv[r]; }
                p += __shfl_down(p, 32);
                p += __shfl_down(p, 16);
                if (quad == 0) atomicAdd(&poolf[ch], p);
#pragma unroll
                for (int r = 0; r < 4; ++r) {
                    int node = mt * 16 + quad * 4 + r;
                    int si = stmap[node];
                    if (si != 255) sts[si * 64 + ch] = hv[r];
                }
            }
        }
        __syncthreads();                                  // B9

        // ---- P6: station MLP, waves 0..3 (ni = wvid), register-resident fc1
        if (wvid < 4) {
            short8 af4[4];
#pragma unroll
            for (int kt = 0; kt < 4; ++kt) {
#pragma unroll
                for (int j = 0; j < 8; ++j) {
                    int k = kt * 32 + quad * 8 + j;
                    float v = 0.f;
                    if (m < 8) v = (k < 64) ? sts[m * 64 + k] : poolf[k - 64] * (1.0f / 256.0f);
                    af4[kt][j] = (short)f2bbits(v);
                }
            }
            f32x4 c = {};
#pragma unroll
            for (int kt = 0; kt < 4; ++kt)
                c = __builtin_amdgcn_mfma_f32_16x16x32_bf16(af4[kt], fc1f[kt], c, 0, 0, 0);
            int ch = wvid * 16 + m;
            float fb = fc1bs[ch], fw = fc2ws[ch];
#pragma unroll
            for (int r = 0; r < 4; ++r) {
                float a = fmaxf(c[r] + fb, 0.f) * fw;
#pragma unroll
                for (int off = 1; off < 16; off <<= 1) a += __shfl_xor(a, off);
                int st = quad * 4 + r;
                if (m == 0 && st < 8) atomicAdd(&spart[st], a);
            }
        }
        __syncthreads();                                  // B10

        if (t < 8) out[g * 8 + t] = spart[t] + fc2bv;
        // next iteration's B1 orders this write before spart re-zero (post-B1)
    }
}

// ---- launch -----------------------------------------------------------------

extern "C" void kernel_launch(void* const* d_in, const int* in_sizes, int n_in,
                              void* d_out, int out_size, void* d_ws, size_t ws_size,
                              hipStream_t stream) {
    const float* x = (const float*)d_in[0];
    const int* ei = (const int*)d_in[1];
    const int* station_ids = (const int*)d_in[2];
    const float* W1 = (const float*)d_in[3];
    const float* b1 = (const float*)d_in[4];
    const float* W2 = (const float*)d_in[5];
    const float* bias2 = (const float*)d_in[6];
    const float* fc1W = (const float*)d_in[7];
    const float* fc1b = (const float*)d_in[8];
    const float* fc2W = (const float*)d_in[9];
    const float* fc2b = (const float*)d_in[10];
    float* out = (float*)d_out;
    (void)in_sizes; (void)n_in; (void)out_size; (void)ws_size;

    char* ws = (char*)d_ws;
    int* gcnt = (int*)ws;                                     // 64 KiB, stride-16 totals
    unsigned short* gout = (unsigned short*)(ws + 0x10000);   // 5.24 MB
    int* hist = (int*)(ws + 0x510000);                        // 1 MB: [tile][graph]

    const int* esrc = ei;
    const int* edst = ei + NEDGES;

    k_hist<<<NTILES, 1024, 0, stream>>>(edst, hist);
    k_scan<<<NGRAPHS, 256, 0, stream>>>(hist, gcnt);
    k_scatter<<<NTILES, 1024, 0, stream>>>(esrc, edst, hist, gout);
    k_fused<<<NBLK, TPB, 0, stream>>>(x, station_ids, W1, b1, W2, bias2,
                                      fc1W, fc1b, fc2W, fc2b, gcnt, gout, out);
}